// Round 6
// baseline (1203.848 us; speedup 1.0000x reference)
//
#include <hip/hip_runtime.h>
#include <math.h>

#define DIM 512
#define NCLS 100
#define NS 2048
#define DD (DIM*DIM)
#define SHRINKV 1e-4f

typedef short bf16x8 __attribute__((ext_vector_type(8)));
typedef short s16x4 __attribute__((ext_vector_type(4)));
typedef float f32x4 __attribute__((ext_vector_type(4)));

static __device__ __forceinline__ short f2bf(float f) {
  unsigned int u = __float_as_uint(f);
  u += 0x7FFFu + ((u >> 16) & 1u);   // round-to-nearest-even
  return (short)(u >> 16);
}

// Build M_k = (1-sh)*(0.5*(SigmaK_k+Sigma)) + sh*I ; accumulate ||RegSigma||_F^2
__global__ __launch_bounds__(256) void prep_kernel(const float* __restrict__ SigmaK,
                                                   const float* __restrict__ Sigma,
                                                   float* __restrict__ M,
                                                   float* __restrict__ aux) {
  int b = blockIdx.x;
  int k = b >> 2, chunk = b & 3;
  const float* Sk = SigmaK + (size_t)k * DD;
  float* Mk = M + (size_t)k * DD;
  int base0 = chunk << 16;
  float fro = 0.f;
  const float oms = 1.0f - SHRINKV;
  for (int it = 0; it < 64; ++it) {
    int idx = base0 + (it << 10) + (threadIdx.x << 2);
    float4 a = *(const float4*)(Sk + idx);
    float4 g = *(const float4*)(Sigma + idx);
    int r = idx >> 9, c = idx & 511;
    float4 reg;
    reg.x = 0.5f*(a.x + g.x); reg.y = 0.5f*(a.y + g.y);
    reg.z = 0.5f*(a.z + g.z); reg.w = 0.5f*(a.w + g.w);
    fro += reg.x*reg.x + reg.y*reg.y + reg.z*reg.z + reg.w*reg.w;
    float4 m;
    m.x = oms*reg.x + ((r == c + 0) ? SHRINKV : 0.f);
    m.y = oms*reg.y + ((r == c + 1) ? SHRINKV : 0.f);
    m.z = oms*reg.z + ((r == c + 2) ? SHRINKV : 0.f);
    m.w = oms*reg.w + ((r == c + 3) ? SHRINKV : 0.f);
    *(float4*)(Mk + idx) = m;
  }
  __shared__ float red[4];
  int lane = threadIdx.x & 63, w = threadIdx.x >> 6;
  for (int o = 32; o > 0; o >>= 1) fro += __shfl_down(fro, o);
  if (lane == 0) red[w] = fro;
  __syncthreads();
  if (threadIdx.x == 0) atomicAdd(&aux[1 + k], red[0] + red[1] + red[2] + red[3]);
}

// Fused fdiag + trsm for panel p. One 256-thread WG per class.
__global__ __launch_bounds__(256) void fdt_kernel(float* __restrict__ M,
                                                  short* __restrict__ Wb, int p) {
  __shared__ float Llds[64 * 68];
  __shared__ float invT[64 * 68];
  __shared__ float TA[64 * 68];
  int kcls = blockIdx.x;
  float* Mk = M + (size_t)kcls * DD;
  short* Wk = Wb + (size_t)kcls * DD;
  int tid = threadIdx.x, lane = tid & 63, wv = tid >> 6;
  int ty = tid >> 4, tx = tid & 15;
  int sr = tid >> 2, sq = (tid & 3) << 4;
  int p0 = p << 6;
  if (wv == 0) {
    float row[64];
    const float* src = Mk + (size_t)(p0 + lane) * DIM + p0;
    #pragma unroll
    for (int c4 = 0; c4 < 64; c4 += 4) {
      float4 v = *(const float4*)(src + c4);
      row[c4] = v.x; row[c4+1] = v.y; row[c4+2] = v.z; row[c4+3] = v.w;
    }
    #pragma unroll
    for (int j = 0; j < 64; ++j) {
      float diagv = __shfl(row[j], j);
      float dv = sqrtf(diagv);
      float rinv = 1.0f / dv;
      float myLj = row[j] * rinv;
      row[j] = myLj;
      #pragma unroll
      for (int c = j + 1; c < 64; ++c)
        row[c] = fmaf(-myLj, __shfl(myLj, c), row[c]);
    }
    #pragma unroll
    for (int c = 0; c < 64; ++c)
      Llds[lane * 68 + c] = (c <= lane) ? row[c] : 0.f;
  }
  __syncthreads();
  if (wv == 0) {
    float w[64];   // lane holds column `lane` of inv: w[r] = inv[r][lane]
    #pragma unroll
    for (int r = 0; r < 64; ++r) {
      float s = 0.f;
      #pragma unroll
      for (int kk = 0; kk + 4 <= r; kk += 4) {
        float4 lv = *(const float4*)(Llds + r*68 + kk);
        s += lv.x*w[kk] + lv.y*w[kk+1] + lv.z*w[kk+2] + lv.w*w[kk+3];
      }
      #pragma unroll
      for (int kk = r & ~3; kk < r; ++kk) s += Llds[r*68 + kk] * w[kk];
      float rhs = ((r == lane) ? 1.0f : 0.0f) - s;
      w[r] = rhs / Llds[r*68 + r];   // exact 0 for r < lane
    }
    #pragma unroll
    for (int r = 0; r < 64; ++r) {
      Mk[(size_t)(p0 + r)*DIM + p0 + lane] = w[r];
      Wk[(size_t)(p0 + r)*DIM + p0 + lane] = f2bf(w[r]);
      invT[lane*68 + r] = w[r];   // invT[m][c] = inv[c][m]
    }
  }
  __syncthreads();
  for (int i = p + 1; i < 8; ++i) {
    {
      const float* a = Mk + (size_t)((i << 6) + sr)*DIM + p0 + sq;
      #pragma unroll
      for (int t4 = 0; t4 < 4; ++t4) {
        float4 va = *(const float4*)(a + 4*t4);
        TA[(sq+4*t4+0)*68+sr]=va.x; TA[(sq+4*t4+1)*68+sr]=va.y;
        TA[(sq+4*t4+2)*68+sr]=va.z; TA[(sq+4*t4+3)*68+sr]=va.w;
      }
    }
    __syncthreads();
    float acc[4][4];
    #pragma unroll
    for (int a2 = 0; a2 < 4; ++a2)
      #pragma unroll
      for (int b2 = 0; b2 < 4; ++b2) acc[a2][b2] = 0.f;
    #pragma unroll 16
    for (int m = 0; m < 64; ++m) {
      float4 av = *(const float4*)(TA + m*68 + (ty << 2));
      float4 bv = *(const float4*)(invT + m*68 + (tx << 2));
      float a4[4] = {av.x, av.y, av.z, av.w};
      float b4[4] = {bv.x, bv.y, bv.z, bv.w};
      #pragma unroll
      for (int ir = 0; ir < 4; ++ir)
        #pragma unroll
        for (int ic = 0; ic < 4; ++ic) acc[ir][ic] += a4[ir] * b4[ic];
    }
    #pragma unroll
    for (int q = 0; q < 4; ++q) {
      float4 v; v.x = acc[q][0]; v.y = acc[q][1]; v.z = acc[q][2]; v.w = acc[q][3];
      *(float4*)(Mk + (size_t)((i << 6) + (ty << 2) + q)*DIM + p0 + (tx << 2)) = v;
    }
    __syncthreads();   // TA reusable next iteration
  }
}

// SYRK: for p < j <= i, A_ij -= L_ip * L_jp^T. One WG per (class, pair).
__global__ __launch_bounds__(256) void syrk_kernel(float* __restrict__ M, int p) {
  __shared__ float TA[64 * 68];
  __shared__ float TB[64 * 68];
  int n = 7 - p;
  int T = n * (n + 1) / 2;
  int cls = blockIdx.x / T;
  int t = blockIdx.x % T;
  int bi = 0;
  while (t > bi) { t -= bi + 1; ++bi; }
  int i = p + 1 + bi, j = p + 1 + t;
  float* Mk = M + (size_t)cls * DD;
  int tid = threadIdx.x;
  int ty = tid >> 4, tx = tid & 15;
  int sr = tid >> 2, sq = (tid & 3) << 4;
  {
    const float* a = Mk + (size_t)((i << 6) + sr)*DIM + (p << 6) + sq;
    const float* b = Mk + (size_t)((j << 6) + sr)*DIM + (p << 6) + sq;
    #pragma unroll
    for (int t4 = 0; t4 < 4; ++t4) {
      float4 va = *(const float4*)(a + 4*t4);
      TA[(sq+4*t4+0)*68+sr]=va.x; TA[(sq+4*t4+1)*68+sr]=va.y;
      TA[(sq+4*t4+2)*68+sr]=va.z; TA[(sq+4*t4+3)*68+sr]=va.w;
      float4 vb = *(const float4*)(b + 4*t4);
      TB[(sq+4*t4+0)*68+sr]=vb.x; TB[(sq+4*t4+1)*68+sr]=vb.y;
      TB[(sq+4*t4+2)*68+sr]=vb.z; TB[(sq+4*t4+3)*68+sr]=vb.w;
    }
  }
  __syncthreads();
  float acc[4][4];
  #pragma unroll
  for (int a = 0; a < 4; ++a)
    #pragma unroll
    for (int b = 0; b < 4; ++b) acc[a][b] = 0.f;
  #pragma unroll 16
  for (int m = 0; m < 64; ++m) {
    float4 av = *(const float4*)(TA + m*68 + (ty << 2));
    float4 bv = *(const float4*)(TB + m*68 + (tx << 2));
    float a4[4] = {av.x, av.y, av.z, av.w};
    float b4[4] = {bv.x, bv.y, bv.z, bv.w};
    #pragma unroll
    for (int ir = 0; ir < 4; ++ir)
      #pragma unroll
      for (int ic = 0; ic < 4; ++ic) acc[ir][ic] += a4[ir] * b4[ic];
  }
  #pragma unroll
  for (int q = 0; q < 4; ++q) {
    float* dst = Mk + (size_t)((i << 6) + (ty << 2) + q)*DIM + (j << 6) + (tx << 2);
    float4 v = *(const float4*)dst;
    v.x -= acc[q][0]; v.y -= acc[q][1]; v.z -= acc[q][2]; v.w -= acc[q][3];
    *(float4*)dst = v;
  }
}

// Tail: panels 4..7 fused per class (fdiag + trsm + syrk in-WG).
__global__ __launch_bounds__(256) void tail_kernel(float* __restrict__ M,
                                                   short* __restrict__ Wb) {
  __shared__ float Llds[64 * 68];
  __shared__ float invT[64 * 68];
  __shared__ float TA[64 * 68];
  __shared__ float TB[64 * 68];
  int kcls = blockIdx.x;
  float* Mk = M + (size_t)kcls * DD;
  short* Wk = Wb + (size_t)kcls * DD;
  int tid = threadIdx.x, lane = tid & 63, wv = tid >> 6;
  int ty = tid >> 4, tx = tid & 15;
  int sr = tid >> 2, sq = (tid & 3) << 4;
  for (int p = 4; p < 8; ++p) {
    int p0 = p << 6;
    __syncthreads();
    if (wv == 0) {
      float row[64];
      const float* src = Mk + (size_t)(p0 + lane) * DIM + p0;
      #pragma unroll
      for (int c4 = 0; c4 < 64; c4 += 4) {
        float4 v = *(const float4*)(src + c4);
        row[c4] = v.x; row[c4+1] = v.y; row[c4+2] = v.z; row[c4+3] = v.w;
      }
      #pragma unroll
      for (int j = 0; j < 64; ++j) {
        float diagv = __shfl(row[j], j);
        float dv = sqrtf(diagv);
        float rinv = 1.0f / dv;
        float myLj = row[j] * rinv;
        row[j] = myLj;
        #pragma unroll
        for (int c = j + 1; c < 64; ++c)
          row[c] = fmaf(-myLj, __shfl(myLj, c), row[c]);
      }
      #pragma unroll
      for (int c = 0; c < 64; ++c)
        Llds[lane * 68 + c] = (c <= lane) ? row[c] : 0.f;
    }
    __syncthreads();
    if (wv == 0) {
      float w[64];
      #pragma unroll
      for (int r = 0; r < 64; ++r) {
        float s = 0.f;
        #pragma unroll
        for (int kk = 0; kk + 4 <= r; kk += 4) {
          float4 lv = *(const float4*)(Llds + r*68 + kk);
          s += lv.x*w[kk] + lv.y*w[kk+1] + lv.z*w[kk+2] + lv.w*w[kk+3];
        }
        #pragma unroll
        for (int kk = r & ~3; kk < r; ++kk) s += Llds[r*68 + kk] * w[kk];
        float rhs = ((r == lane) ? 1.0f : 0.0f) - s;
        w[r] = rhs / Llds[r*68 + r];
      }
      #pragma unroll
      for (int r = 0; r < 64; ++r) {
        Mk[(size_t)(p0 + r)*DIM + p0 + lane] = w[r];
        Wk[(size_t)(p0 + r)*DIM + p0 + lane] = f2bf(w[r]);
        invT[lane*68 + r] = w[r];
      }
    }
    __syncthreads();
    for (int i = p + 1; i < 8; ++i) {
      {
        const float* a = Mk + (size_t)((i << 6) + sr)*DIM + p0 + sq;
        #pragma unroll
        for (int t4 = 0; t4 < 4; ++t4) {
          float4 va = *(const float4*)(a + 4*t4);
          TA[(sq+4*t4+0)*68+sr]=va.x; TA[(sq+4*t4+1)*68+sr]=va.y;
          TA[(sq+4*t4+2)*68+sr]=va.z; TA[(sq+4*t4+3)*68+sr]=va.w;
        }
      }
      __syncthreads();
      float acc[4][4];
      #pragma unroll
      for (int a2 = 0; a2 < 4; ++a2)
        #pragma unroll
        for (int b2 = 0; b2 < 4; ++b2) acc[a2][b2] = 0.f;
      #pragma unroll 16
      for (int m = 0; m < 64; ++m) {
        float4 av = *(const float4*)(TA + m*68 + (ty << 2));
        float4 bv = *(const float4*)(invT + m*68 + (tx << 2));
        float a4[4] = {av.x, av.y, av.z, av.w};
        float b4[4] = {bv.x, bv.y, bv.z, bv.w};
        #pragma unroll
        for (int ir = 0; ir < 4; ++ir)
          #pragma unroll
          for (int ic = 0; ic < 4; ++ic) acc[ir][ic] += a4[ir] * b4[ic];
      }
      #pragma unroll
      for (int q = 0; q < 4; ++q) {
        float4 v; v.x = acc[q][0]; v.y = acc[q][1]; v.z = acc[q][2]; v.w = acc[q][3];
        *(float4*)(Mk + (size_t)((i << 6) + (ty << 2) + q)*DIM + p0 + (tx << 2)) = v;
      }
      __syncthreads();
    }
    for (int i = p + 1; i < 8; ++i) {
      for (int j = p + 1; j <= i; ++j) {
        {
          const float* a = Mk + (size_t)((i << 6) + sr)*DIM + p0 + sq;
          const float* b = Mk + (size_t)((j << 6) + sr)*DIM + p0 + sq;
          #pragma unroll
          for (int t4 = 0; t4 < 4; ++t4) {
            float4 va = *(const float4*)(a + 4*t4);
            TA[(sq+4*t4+0)*68+sr]=va.x; TA[(sq+4*t4+1)*68+sr]=va.y;
            TA[(sq+4*t4+2)*68+sr]=va.z; TA[(sq+4*t4+3)*68+sr]=va.w;
            float4 vb = *(const float4*)(b + 4*t4);
            TB[(sq+4*t4+0)*68+sr]=vb.x; TB[(sq+4*t4+1)*68+sr]=vb.y;
            TB[(sq+4*t4+2)*68+sr]=vb.z; TB[(sq+4*t4+3)*68+sr]=vb.w;
          }
        }
        __syncthreads();
        float acc[4][4];
        #pragma unroll
        for (int a2 = 0; a2 < 4; ++a2)
          #pragma unroll
          for (int b2 = 0; b2 < 4; ++b2) acc[a2][b2] = 0.f;
        #pragma unroll 16
        for (int m = 0; m < 64; ++m) {
          float4 av = *(const float4*)(TA + m*68 + (ty << 2));
          float4 bv = *(const float4*)(TB + m*68 + (tx << 2));
          float a4[4] = {av.x, av.y, av.z, av.w};
          float b4[4] = {bv.x, bv.y, bv.z, bv.w};
          #pragma unroll
          for (int ir = 0; ir < 4; ++ir)
            #pragma unroll
            for (int ic = 0; ic < 4; ++ic) acc[ir][ic] += a4[ir] * b4[ic];
        }
        #pragma unroll
        for (int q = 0; q < 4; ++q) {
          float* dst = Mk + (size_t)((i << 6) + (ty << 2) + q)*DIM + (j << 6) + (tx << 2);
          float4 v = *(const float4*)dst;
          v.x -= acc[q][0]; v.y -= acc[q][1]; v.z -= acc[q][2]; v.w -= acc[q][3];
          *(float4*)dst = v;
        }
        __syncthreads();
      }
    }
  }
}

// Column sweep: one WG per (class, column j in 0..6). Computes, for i=j+1..7:
// W_ij = -W_ii * (sum_{k=j}^{i-1} L_ik * W_kj). All deps are intra-column, so
// the i-loop is serial in-WG (W f32 in M's upper triangle: block (j,k) = W_kj).
__global__ __launch_bounds__(256) void colsweep_kernel(float* __restrict__ M,
                                                       short* __restrict__ Wb) {
  __shared__ float TL[64 * 68];
  __shared__ float TW[64 * 68];
  int cls = blockIdx.x / 7;
  int j = blockIdx.x % 7;
  float* Mk = M + (size_t)cls * DD;
  short* Wk = Wb + (size_t)cls * DD;
  int tid = threadIdx.x;
  int ty = tid >> 4, tx = tid & 15;
  int sr = tid >> 2, sq = (tid & 3) << 4;
  for (int i = j + 1; i < 8; ++i) {
    float acc[4][4];
    #pragma unroll
    for (int a = 0; a < 4; ++a)
      #pragma unroll
      for (int b = 0; b < 4; ++b) acc[a][b] = 0.f;
    for (int k = j; k < i; ++k) {
      __syncthreads();
      {
        const float* a = Mk + (size_t)((i << 6) + sr)*DIM + (k << 6) + sq;
        const float* b = Mk + (size_t)((j << 6) + sr)*DIM + (k << 6) + sq;
        #pragma unroll
        for (int t4 = 0; t4 < 4; ++t4) {
          float4 va = *(const float4*)(a + 4*t4);
          TL[(sq+4*t4+0)*68+sr]=va.x; TL[(sq+4*t4+1)*68+sr]=va.y;
          TL[(sq+4*t4+2)*68+sr]=va.z; TL[(sq+4*t4+3)*68+sr]=va.w;
          *(float4*)(TW + sr*68 + sq + 4*t4) = *(const float4*)(b + 4*t4);
        }
      }
      __syncthreads();
      #pragma unroll 16
      for (int m = 0; m < 64; ++m) {
        float4 av = *(const float4*)(TL + m*68 + (ty << 2));
        float4 bv = *(const float4*)(TW + m*68 + (tx << 2));
        float a4[4] = {av.x, av.y, av.z, av.w};
        float b4[4] = {bv.x, bv.y, bv.z, bv.w};
        #pragma unroll
        for (int ir = 0; ir < 4; ++ir)
          #pragma unroll
          for (int ic = 0; ic < 4; ++ic) acc[ir][ic] += a4[ir] * b4[ic];
      }
    }
    __syncthreads();
    #pragma unroll
    for (int q = 0; q < 4; ++q) {
      float4 v; v.x = acc[q][0]; v.y = acc[q][1]; v.z = acc[q][2]; v.w = acc[q][3];
      *(float4*)(TW + ((ty << 2) + q)*68 + (tx << 2)) = v;
    }
    {
      const float* a = Mk + (size_t)((i << 6) + sr)*DIM + (i << 6) + sq;
      #pragma unroll
      for (int t4 = 0; t4 < 4; ++t4) {
        float4 va = *(const float4*)(a + 4*t4);
        TL[(sq+4*t4+0)*68+sr]=va.x; TL[(sq+4*t4+1)*68+sr]=va.y;
        TL[(sq+4*t4+2)*68+sr]=va.z; TL[(sq+4*t4+3)*68+sr]=va.w;
      }
    }
    __syncthreads();
    float r2[4][4];
    #pragma unroll
    for (int a = 0; a < 4; ++a)
      #pragma unroll
      for (int b = 0; b < 4; ++b) r2[a][b] = 0.f;
    #pragma unroll 16
    for (int m = 0; m < 64; ++m) {
      float4 av = *(const float4*)(TL + m*68 + (ty << 2));
      float4 bv = *(const float4*)(TW + m*68 + (tx << 2));
      float a4[4] = {av.x, av.y, av.z, av.w};
      float b4[4] = {bv.x, bv.y, bv.z, bv.w};
      #pragma unroll
      for (int ir = 0; ir < 4; ++ir)
        #pragma unroll
        for (int ic = 0; ic < 4; ++ic) r2[ir][ic] += a4[ir] * b4[ic];
    }
    #pragma unroll
    for (int q = 0; q < 4; ++q) {
      int a = (ty << 2) + q;
      float4 v; v.x = -r2[q][0]; v.y = -r2[q][1]; v.z = -r2[q][2]; v.w = -r2[q][3];
      *(float4*)(Mk + (size_t)((j << 6) + a)*DIM + (i << 6) + (tx << 2)) = v;
      s16x4 h;
      h[0] = f2bf(v.x); h[1] = f2bf(v.y); h[2] = f2bf(v.z); h[3] = f2bf(v.w);
      *(s16x4*)(Wk + (size_t)((i << 6) + a)*DIM + (j << 6) + (tx << 2)) = h;
    }
  }
}

// scores via bf16 MFMA. jt split into 4 groups of 2 (32-reg accumulator);
// diff tiles double-buffered in LDS (re-staged per group), W tiles
// double-buffered with issue-early/write-late pipeline. Compile-time 36-stage
// schedule; XCD-aware class swizzle for W L2 locality.
__global__ __launch_bounds__(256, 2) void score_kernel(const float* __restrict__ X,
                                                       const float* __restrict__ muK,
                                                       const float* __restrict__ cK,
                                                       const short* __restrict__ W,
                                                       const float* __restrict__ aux,
                                                       float* __restrict__ out) {
  __shared__ __align__(16) short WBs[2][4096];
  __shared__ __align__(16) short DBs[2][4096];
  __shared__ float sred[4];
  // XCD swizzle: 3200 blocks; XCD x gets contiguous wg range [x*400,(x+1)*400)
  int bid = blockIdx.x;
  int wg = ((bid & 7) * 400) + (bid >> 3);
  int kc = wg >> 5;
  int n0 = (wg & 31) << 6;
  int tid = threadIdx.x;
  int lane = tid & 63, wv = tid >> 6;
  int srow = tid >> 2;
  int sc4 = (tid & 3) << 4;
  const short* Wk = W + (size_t)kc * DD;
  const float* mu = muK + (size_t)kc * DIM;
  int r16 = lane & 15;
  int k8 = (lane >> 4) << 3;
  int arow = (wv << 4) + r16;
  int sb0 = ((srow << 7) + (sc4 << 1)) ^ ((srow & 7) << 4);
  int sb1 = ((srow << 7) + (sc4 << 1) + 16) ^ ((srow & 7) << 4);

  // stage diff chunk dc (f32 global -> bf16 LDS), buffer par
  auto stage_diff = [&](int dc, int par) {
    const float* xr = X + (size_t)(n0 + srow)*DIM + (dc << 6) + sc4;
    const float* mr = mu + (dc << 6) + sc4;
    float4 x0 = *(const float4*)(xr + 0);
    float4 x1 = *(const float4*)(xr + 4);
    float4 x2 = *(const float4*)(xr + 8);
    float4 x3 = *(const float4*)(xr + 12);
    float4 m0 = *(const float4*)(mr + 0);
    float4 m1 = *(const float4*)(mr + 4);
    float4 m2 = *(const float4*)(mr + 8);
    float4 m3 = *(const float4*)(mr + 12);
    bf16x8 h0, h1;
    h0[0]=f2bf(x0.x-m0.x); h0[1]=f2bf(x0.y-m0.y); h0[2]=f2bf(x0.z-m0.z); h0[3]=f2bf(x0.w-m0.w);
    h0[4]=f2bf(x1.x-m1.x); h0[5]=f2bf(x1.y-m1.y); h0[6]=f2bf(x1.z-m1.z); h0[7]=f2bf(x1.w-m1.w);
    h1[0]=f2bf(x2.x-m2.x); h1[1]=f2bf(x2.y-m2.y); h1[2]=f2bf(x2.z-m2.z); h1[3]=f2bf(x2.w-m2.w);
    h1[4]=f2bf(x3.x-m3.x); h1[5]=f2bf(x3.y-m3.y); h1[6]=f2bf(x3.z-m3.z); h1[7]=f2bf(x3.w-m3.w);
    *(bf16x8*)((char*)DBs[par] + sb0) = h0;
    *(bf16x8*)((char*)DBs[par] + sb1) = h1;
  };

  // 36-stage schedule: 4 groups of 2 jt's; dc-outer within group (padded to 38)
  constexpr int SJT[38] = {0,1,1, 2,3,2,3,2,3,3, 4,5,4,5,4,5,4,5,4,5,5,
                           6,7,6,7,6,7,6,7,6,7,6,7,6,7,7, 0,0};
  constexpr int SDC[38] = {0,0,1, 0,0,1,1,2,2,3, 0,0,1,1,2,2,3,3,4,4,5,
                           0,0,1,1,2,2,3,3,4,4,5,5,6,6,7, 0,0};
  constexpr int DIX[38] = {0,0,1, 2,2,3,3,4,4,5, 6,6,7,7,8,8,9,9,10,10,11,
                           12,12,13,13,14,14,15,15,16,16,17,17,18,18,19, 0,0};
  constexpr int DCD[20] = {0,1, 0,1,2,3, 0,1,2,3,4,5, 0,1,2,3,4,5,6,7};

  // prologue: diff block 0, W pipeline (stage 0 in LDS, stage 1 in regs)
  stage_diff(0, 0);
  uint4 rg[2][2];
  {
    const uint4* p0 = (const uint4*)(Wk + (size_t)srow*DIM + sc4);          // (0,0)
    rg[0][0] = p0[0]; rg[0][1] = p0[1];
  }
  *(uint4*)((char*)WBs[0] + sb0) = rg[0][0];
  *(uint4*)((char*)WBs[0] + sb1) = rg[0][1];
  {
    const uint4* p1 = (const uint4*)(Wk + (size_t)(64 + srow)*DIM + sc4);   // (1,0)
    rg[1][0] = p1[0]; rg[1][1] = p1[1];
  }
  {
    float v = (tid < NCLS) ? cK[tid] : 0.f;
    #pragma unroll
    for (int o = 32; o > 0; o >>= 1) v += __shfl_xor(v, o);
    if (lane == 0) sred[wv] = v;
  }
  __syncthreads();
  float sumck = sred[0] + sred[1] + sred[2] + sred[3];

  float qp[4] = {0.f, 0.f, 0.f, 0.f};
  f32x4 acc[2][4];
  #pragma unroll
  for (int a = 0; a < 2; ++a)
    #pragma unroll
    for (int jj = 0; jj < 4; ++jj) { acc[a][jj][0]=0.f; acc[a][jj][1]=0.f; acc[a][jj][2]=0.f; acc[a][jj][3]=0.f; }
  bf16x8 af0, af1;

  #pragma unroll
  for (int s = 0; s < 36; ++s) {
    const int jt = SJT[s], d = DIX[s];
    const bool fb = (s == 0) || (DIX[s-1] != d);
    if (fb) {
      if (d < 19) stage_diff(DCD[d+1], (d+1) & 1);   // next diff block
      // A-fragments for this dc block
      af0 = *(const bf16x8*)((const char*)DBs[d & 1] +
            (((arow << 7) + (k8 << 1)) ^ ((arow & 7) << 4)));
      af1 = *(const bf16x8*)((const char*)DBs[d & 1] +
            (((arow << 7) + ((32 + k8) << 1)) ^ ((arow & 7) << 4)));
    }
    if (s + 1 < 36) {   // write data(s+1) into the other W buffer
      *(uint4*)((char*)WBs[(s+1) & 1] + sb0) = rg[(s+1) & 1][0];
      *(uint4*)((char*)WBs[(s+1) & 1] + sb1) = rg[(s+1) & 1][1];
    }
    if (s + 2 < 36) {   // issue loads for data(s+2)
      const uint4* pp = (const uint4*)(Wk + (size_t)((SJT[s+2] << 6) + srow)*DIM +
                                       (SDC[s+2] << 6) + sc4);
      rg[s & 1][0] = pp[0]; rg[s & 1][1] = pp[1];
    }
    __builtin_amdgcn_s_setprio(1);
    #pragma unroll
    for (int ks = 0; ks < 2; ++ks) {
      bf16x8 afk = ks ? af1 : af0;
      #pragma unroll
      for (int jj = 0; jj < 4; ++jj) {
        int brow = (jj << 4) + r16;
        bf16x8 bfr = *(const bf16x8*)((const char*)WBs[s & 1] +
                     (((brow << 7) + (((ks << 5) + k8) << 1)) ^ ((brow & 7) << 4)));
        acc[jt & 1][jj] = __builtin_amdgcn_mfma_f32_16x16x32_bf16(afk, bfr, acc[jt & 1][jj], 0, 0, 0);
      }
    }
    __builtin_amdgcn_s_setprio(0);
    __syncthreads();
    if (s == 2 || s == 9 || s == 20 || s == 35) {   // group end: square & reset
      #pragma unroll
      for (int a = 0; a < 2; ++a)
        #pragma unroll
        for (int jj = 0; jj < 4; ++jj)
          #pragma unroll
          for (int r = 0; r < 4; ++r) {
            float y = acc[a][jj][r]; qp[r] += y * y;
            acc[a][jj][r] = 0.f;
          }
    }
  }
  #pragma unroll
  for (int r = 0; r < 4; ++r) {
    qp[r] += __shfl_xor(qp[r], 1);
    qp[r] += __shfl_xor(qp[r], 2);
    qp[r] += __shfl_xor(qp[r], 4);
    qp[r] += __shfl_xor(qp[r], 8);
  }
  float ck = cK[kc];
  float base;
  if (ck == 0.f) base = -INFINITY;
  else base = logf(ck) - logf(sumck) - 0.25f * logf(aux[1 + kc]);
  if ((lane & 15) == 0) {
    int nbase = n0 + (wv << 4) + ((lane >> 4) << 2);
    #pragma unroll
    for (int r = 0; r < 4; ++r)
      out[(size_t)(nbase + r)*NCLS + kc] = base - 0.5f * qp[r];
  }
}

extern "C" void kernel_launch(void* const* d_in, const int* in_sizes, int n_in,
                              void* d_out, int out_size, void* d_ws, size_t ws_size,
                              hipStream_t stream) {
  (void)in_sizes; (void)n_in; (void)out_size; (void)ws_size;
  const float* X      = (const float*)d_in[0];
  const float* muK    = (const float*)d_in[1];
  const float* SigmaK = (const float*)d_in[2];
  const float* Sigma  = (const float*)d_in[3];
  const float* cK     = (const float*)d_in[4];
  float* out = (float*)d_out;
  char* ws = (char*)d_ws;
  float* M   = (float*)ws;                                   // 104857600 B
  short* W   = (short*)(ws + (size_t)NCLS * DD * 4);         //  52428800 B
  float* aux = (float*)(ws + (size_t)NCLS * DD * 6);         //       404 B

  hipMemsetAsync(aux, 0, (1 + NCLS) * sizeof(float), stream);
  prep_kernel<<<400, 256, 0, stream>>>(SigmaK, Sigma, M, aux);
  for (int p = 0; p < 4; ++p) {
    fdt_kernel<<<NCLS, 256, 0, stream>>>(M, W, p);
    int n = 7 - p;
    syrk_kernel<<<NCLS * (n * (n + 1) / 2), 256, 0, stream>>>(M, p);
  }
  tail_kernel<<<NCLS, 256, 0, stream>>>(M, W);
  colsweep_kernel<<<NCLS * 7, 256, 0, stream>>>(M, W);
  score_kernel<<<NCLS * 32, 256, 0, stream>>>(X, muK, cK, W, aux, out);
}

// Round 7
// 1110.931 us; speedup vs baseline: 1.0836x; 1.0836x over previous
//
#include <hip/hip_runtime.h>
#include <math.h>

#define DIM 512
#define NCLS 100
#define NS 2048
#define DD (DIM*DIM)
#define SHRINKV 1e-4f

typedef short bf16x8 __attribute__((ext_vector_type(8)));
typedef short s16x4 __attribute__((ext_vector_type(4)));
typedef float f32x4 __attribute__((ext_vector_type(4)));

static __device__ __forceinline__ short f2bf(float f) {
  unsigned int u = __float_as_uint(f);
  u += 0x7FFFu + ((u >> 16) & 1u);   // round-to-nearest-even
  return (short)(u >> 16);
}

// Build M_k = (1-sh)*(0.5*(SigmaK_k+Sigma)) + sh*I ; accumulate ||RegSigma||_F^2
__global__ __launch_bounds__(256) void prep_kernel(const float* __restrict__ SigmaK,
                                                   const float* __restrict__ Sigma,
                                                   float* __restrict__ M,
                                                   float* __restrict__ aux) {
  int b = blockIdx.x;
  int k = b >> 2, chunk = b & 3;
  const float* Sk = SigmaK + (size_t)k * DD;
  float* Mk = M + (size_t)k * DD;
  int base0 = chunk << 16;
  float fro = 0.f;
  const float oms = 1.0f - SHRINKV;
  for (int it = 0; it < 64; ++it) {
    int idx = base0 + (it << 10) + (threadIdx.x << 2);
    float4 a = *(const float4*)(Sk + idx);
    float4 g = *(const float4*)(Sigma + idx);
    int r = idx >> 9, c = idx & 511;
    float4 reg;
    reg.x = 0.5f*(a.x + g.x); reg.y = 0.5f*(a.y + g.y);
    reg.z = 0.5f*(a.z + g.z); reg.w = 0.5f*(a.w + g.w);
    fro += reg.x*reg.x + reg.y*reg.y + reg.z*reg.z + reg.w*reg.w;
    float4 m;
    m.x = oms*reg.x + ((r == c + 0) ? SHRINKV : 0.f);
    m.y = oms*reg.y + ((r == c + 1) ? SHRINKV : 0.f);
    m.z = oms*reg.z + ((r == c + 2) ? SHRINKV : 0.f);
    m.w = oms*reg.w + ((r == c + 3) ? SHRINKV : 0.f);
    *(float4*)(Mk + idx) = m;
  }
  __shared__ float red[4];
  int lane = threadIdx.x & 63, w = threadIdx.x >> 6;
  for (int o = 32; o > 0; o >>= 1) fro += __shfl_down(fro, o);
  if (lane == 0) red[w] = fro;
  __syncthreads();
  if (threadIdx.x == 0) atomicAdd(&aux[1 + k], red[0] + red[1] + red[2] + red[3]);
}

// Fused fdiag + trsm for panel p. One 256-thread WG per class.
__global__ __launch_bounds__(256) void fdt_kernel(float* __restrict__ M,
                                                  short* __restrict__ Wb, int p) {
  __shared__ float Llds[64 * 68];
  __shared__ float invT[64 * 68];
  __shared__ float TA[64 * 68];
  int kcls = blockIdx.x;
  float* Mk = M + (size_t)kcls * DD;
  short* Wk = Wb + (size_t)kcls * DD;
  int tid = threadIdx.x, lane = tid & 63, wv = tid >> 6;
  int ty = tid >> 4, tx = tid & 15;
  int sr = tid >> 2, sq = (tid & 3) << 4;
  int p0 = p << 6;
  if (wv == 0) {
    float row[64];
    const float* src = Mk + (size_t)(p0 + lane) * DIM + p0;
    #pragma unroll
    for (int c4 = 0; c4 < 64; c4 += 4) {
      float4 v = *(const float4*)(src + c4);
      row[c4] = v.x; row[c4+1] = v.y; row[c4+2] = v.z; row[c4+3] = v.w;
    }
    #pragma unroll
    for (int j = 0; j < 64; ++j) {
      float diagv = __shfl(row[j], j);
      float dv = sqrtf(diagv);
      float rinv = 1.0f / dv;
      float myLj = row[j] * rinv;
      row[j] = myLj;
      #pragma unroll
      for (int c = j + 1; c < 64; ++c)
        row[c] = fmaf(-myLj, __shfl(myLj, c), row[c]);
    }
    #pragma unroll
    for (int c = 0; c < 64; ++c)
      Llds[lane * 68 + c] = (c <= lane) ? row[c] : 0.f;
  }
  __syncthreads();
  if (wv == 0) {
    float w[64];   // lane holds column `lane` of inv: w[r] = inv[r][lane]
    #pragma unroll
    for (int r = 0; r < 64; ++r) {
      float s = 0.f;
      #pragma unroll
      for (int kk = 0; kk + 4 <= r; kk += 4) {
        float4 lv = *(const float4*)(Llds + r*68 + kk);
        s += lv.x*w[kk] + lv.y*w[kk+1] + lv.z*w[kk+2] + lv.w*w[kk+3];
      }
      #pragma unroll
      for (int kk = r & ~3; kk < r; ++kk) s += Llds[r*68 + kk] * w[kk];
      float rhs = ((r == lane) ? 1.0f : 0.0f) - s;
      w[r] = rhs / Llds[r*68 + r];   // exact 0 for r < lane
    }
    #pragma unroll
    for (int r = 0; r < 64; ++r) {
      Mk[(size_t)(p0 + r)*DIM + p0 + lane] = w[r];
      Wk[(size_t)(p0 + r)*DIM + p0 + lane] = f2bf(w[r]);
      invT[lane*68 + r] = w[r];   // invT[m][c] = inv[c][m]
    }
  }
  __syncthreads();
  for (int i = p + 1; i < 8; ++i) {
    {
      const float* a = Mk + (size_t)((i << 6) + sr)*DIM + p0 + sq;
      #pragma unroll
      for (int t4 = 0; t4 < 4; ++t4) {
        float4 va = *(const float4*)(a + 4*t4);
        TA[(sq+4*t4+0)*68+sr]=va.x; TA[(sq+4*t4+1)*68+sr]=va.y;
        TA[(sq+4*t4+2)*68+sr]=va.z; TA[(sq+4*t4+3)*68+sr]=va.w;
      }
    }
    __syncthreads();
    float acc[4][4];
    #pragma unroll
    for (int a2 = 0; a2 < 4; ++a2)
      #pragma unroll
      for (int b2 = 0; b2 < 4; ++b2) acc[a2][b2] = 0.f;
    #pragma unroll 16
    for (int m = 0; m < 64; ++m) {
      float4 av = *(const float4*)(TA + m*68 + (ty << 2));
      float4 bv = *(const float4*)(invT + m*68 + (tx << 2));
      float a4[4] = {av.x, av.y, av.z, av.w};
      float b4[4] = {bv.x, bv.y, bv.z, bv.w};
      #pragma unroll
      for (int ir = 0; ir < 4; ++ir)
        #pragma unroll
        for (int ic = 0; ic < 4; ++ic) acc[ir][ic] += a4[ir] * b4[ic];
    }
    #pragma unroll
    for (int q = 0; q < 4; ++q) {
      float4 v; v.x = acc[q][0]; v.y = acc[q][1]; v.z = acc[q][2]; v.w = acc[q][3];
      *(float4*)(Mk + (size_t)((i << 6) + (ty << 2) + q)*DIM + p0 + (tx << 2)) = v;
    }
    __syncthreads();   // TA reusable next iteration
  }
}

// SYRK: for p < j <= i, A_ij -= L_ip * L_jp^T. One WG per (class, pair).
__global__ __launch_bounds__(256) void syrk_kernel(float* __restrict__ M, int p) {
  __shared__ float TA[64 * 68];
  __shared__ float TB[64 * 68];
  int n = 7 - p;
  int T = n * (n + 1) / 2;
  int cls = blockIdx.x / T;
  int t = blockIdx.x % T;
  int bi = 0;
  while (t > bi) { t -= bi + 1; ++bi; }
  int i = p + 1 + bi, j = p + 1 + t;
  float* Mk = M + (size_t)cls * DD;
  int tid = threadIdx.x;
  int ty = tid >> 4, tx = tid & 15;
  int sr = tid >> 2, sq = (tid & 3) << 4;
  {
    const float* a = Mk + (size_t)((i << 6) + sr)*DIM + (p << 6) + sq;
    const float* b = Mk + (size_t)((j << 6) + sr)*DIM + (p << 6) + sq;
    #pragma unroll
    for (int t4 = 0; t4 < 4; ++t4) {
      float4 va = *(const float4*)(a + 4*t4);
      TA[(sq+4*t4+0)*68+sr]=va.x; TA[(sq+4*t4+1)*68+sr]=va.y;
      TA[(sq+4*t4+2)*68+sr]=va.z; TA[(sq+4*t4+3)*68+sr]=va.w;
      float4 vb = *(const float4*)(b + 4*t4);
      TB[(sq+4*t4+0)*68+sr]=vb.x; TB[(sq+4*t4+1)*68+sr]=vb.y;
      TB[(sq+4*t4+2)*68+sr]=vb.z; TB[(sq+4*t4+3)*68+sr]=vb.w;
    }
  }
  __syncthreads();
  float acc[4][4];
  #pragma unroll
  for (int a = 0; a < 4; ++a)
    #pragma unroll
    for (int b = 0; b < 4; ++b) acc[a][b] = 0.f;
  #pragma unroll 16
  for (int m = 0; m < 64; ++m) {
    float4 av = *(const float4*)(TA + m*68 + (ty << 2));
    float4 bv = *(const float4*)(TB + m*68 + (tx << 2));
    float a4[4] = {av.x, av.y, av.z, av.w};
    float b4[4] = {bv.x, bv.y, bv.z, bv.w};
    #pragma unroll
    for (int ir = 0; ir < 4; ++ir)
      #pragma unroll
      for (int ic = 0; ic < 4; ++ic) acc[ir][ic] += a4[ir] * b4[ic];
  }
  #pragma unroll
  for (int q = 0; q < 4; ++q) {
    float* dst = Mk + (size_t)((i << 6) + (ty << 2) + q)*DIM + (j << 6) + (tx << 2);
    float4 v = *(const float4*)dst;
    v.x -= acc[q][0]; v.y -= acc[q][1]; v.z -= acc[q][2]; v.w -= acc[q][3];
    *(float4*)dst = v;
  }
}

// Tail: panels 4..7 fused per class (fdiag + trsm + syrk in-WG).
__global__ __launch_bounds__(256) void tail_kernel(float* __restrict__ M,
                                                   short* __restrict__ Wb) {
  __shared__ float Llds[64 * 68];
  __shared__ float invT[64 * 68];
  __shared__ float TA[64 * 68];
  __shared__ float TB[64 * 68];
  int kcls = blockIdx.x;
  float* Mk = M + (size_t)kcls * DD;
  short* Wk = Wb + (size_t)kcls * DD;
  int tid = threadIdx.x, lane = tid & 63, wv = tid >> 6;
  int ty = tid >> 4, tx = tid & 15;
  int sr = tid >> 2, sq = (tid & 3) << 4;
  for (int p = 4; p < 8; ++p) {
    int p0 = p << 6;
    __syncthreads();
    if (wv == 0) {
      float row[64];
      const float* src = Mk + (size_t)(p0 + lane) * DIM + p0;
      #pragma unroll
      for (int c4 = 0; c4 < 64; c4 += 4) {
        float4 v = *(const float4*)(src + c4);
        row[c4] = v.x; row[c4+1] = v.y; row[c4+2] = v.z; row[c4+3] = v.w;
      }
      #pragma unroll
      for (int j = 0; j < 64; ++j) {
        float diagv = __shfl(row[j], j);
        float dv = sqrtf(diagv);
        float rinv = 1.0f / dv;
        float myLj = row[j] * rinv;
        row[j] = myLj;
        #pragma unroll
        for (int c = j + 1; c < 64; ++c)
          row[c] = fmaf(-myLj, __shfl(myLj, c), row[c]);
      }
      #pragma unroll
      for (int c = 0; c < 64; ++c)
        Llds[lane * 68 + c] = (c <= lane) ? row[c] : 0.f;
    }
    __syncthreads();
    if (wv == 0) {
      float w[64];
      #pragma unroll
      for (int r = 0; r < 64; ++r) {
        float s = 0.f;
        #pragma unroll
        for (int kk = 0; kk + 4 <= r; kk += 4) {
          float4 lv = *(const float4*)(Llds + r*68 + kk);
          s += lv.x*w[kk] + lv.y*w[kk+1] + lv.z*w[kk+2] + lv.w*w[kk+3];
        }
        #pragma unroll
        for (int kk = r & ~3; kk < r; ++kk) s += Llds[r*68 + kk] * w[kk];
        float rhs = ((r == lane) ? 1.0f : 0.0f) - s;
        w[r] = rhs / Llds[r*68 + r];
      }
      #pragma unroll
      for (int r = 0; r < 64; ++r) {
        Mk[(size_t)(p0 + r)*DIM + p0 + lane] = w[r];
        Wk[(size_t)(p0 + r)*DIM + p0 + lane] = f2bf(w[r]);
        invT[lane*68 + r] = w[r];
      }
    }
    __syncthreads();
    for (int i = p + 1; i < 8; ++i) {
      {
        const float* a = Mk + (size_t)((i << 6) + sr)*DIM + p0 + sq;
        #pragma unroll
        for (int t4 = 0; t4 < 4; ++t4) {
          float4 va = *(const float4*)(a + 4*t4);
          TA[(sq+4*t4+0)*68+sr]=va.x; TA[(sq+4*t4+1)*68+sr]=va.y;
          TA[(sq+4*t4+2)*68+sr]=va.z; TA[(sq+4*t4+3)*68+sr]=va.w;
        }
      }
      __syncthreads();
      float acc[4][4];
      #pragma unroll
      for (int a2 = 0; a2 < 4; ++a2)
        #pragma unroll
        for (int b2 = 0; b2 < 4; ++b2) acc[a2][b2] = 0.f;
      #pragma unroll 16
      for (int m = 0; m < 64; ++m) {
        float4 av = *(const float4*)(TA + m*68 + (ty << 2));
        float4 bv = *(const float4*)(invT + m*68 + (tx << 2));
        float a4[4] = {av.x, av.y, av.z, av.w};
        float b4[4] = {bv.x, bv.y, bv.z, bv.w};
        #pragma unroll
        for (int ir = 0; ir < 4; ++ir)
          #pragma unroll
          for (int ic = 0; ic < 4; ++ic) acc[ir][ic] += a4[ir] * b4[ic];
      }
      #pragma unroll
      for (int q = 0; q < 4; ++q) {
        float4 v; v.x = acc[q][0]; v.y = acc[q][1]; v.z = acc[q][2]; v.w = acc[q][3];
        *(float4*)(Mk + (size_t)((i << 6) + (ty << 2) + q)*DIM + p0 + (tx << 2)) = v;
      }
      __syncthreads();
    }
    for (int i = p + 1; i < 8; ++i) {
      for (int j = p + 1; j <= i; ++j) {
        {
          const float* a = Mk + (size_t)((i << 6) + sr)*DIM + p0 + sq;
          const float* b = Mk + (size_t)((j << 6) + sr)*DIM + p0 + sq;
          #pragma unroll
          for (int t4 = 0; t4 < 4; ++t4) {
            float4 va = *(const float4*)(a + 4*t4);
            TA[(sq+4*t4+0)*68+sr]=va.x; TA[(sq+4*t4+1)*68+sr]=va.y;
            TA[(sq+4*t4+2)*68+sr]=va.z; TA[(sq+4*t4+3)*68+sr]=va.w;
            float4 vb = *(const float4*)(b + 4*t4);
            TB[(sq+4*t4+0)*68+sr]=vb.x; TB[(sq+4*t4+1)*68+sr]=vb.y;
            TB[(sq+4*t4+2)*68+sr]=vb.z; TB[(sq+4*t4+3)*68+sr]=vb.w;
          }
        }
        __syncthreads();
        float acc[4][4];
        #pragma unroll
        for (int a2 = 0; a2 < 4; ++a2)
          #pragma unroll
          for (int b2 = 0; b2 < 4; ++b2) acc[a2][b2] = 0.f;
        #pragma unroll 16
        for (int m = 0; m < 64; ++m) {
          float4 av = *(const float4*)(TA + m*68 + (ty << 2));
          float4 bv = *(const float4*)(TB + m*68 + (tx << 2));
          float a4[4] = {av.x, av.y, av.z, av.w};
          float b4[4] = {bv.x, bv.y, bv.z, bv.w};
          #pragma unroll
          for (int ir = 0; ir < 4; ++ir)
            #pragma unroll
            for (int ic = 0; ic < 4; ++ic) acc[ir][ic] += a4[ir] * b4[ic];
        }
        #pragma unroll
        for (int q = 0; q < 4; ++q) {
          float* dst = Mk + (size_t)((i << 6) + (ty << 2) + q)*DIM + (j << 6) + (tx << 2);
          float4 v = *(const float4*)dst;
          v.x -= acc[q][0]; v.y -= acc[q][1]; v.z -= acc[q][2]; v.w -= acc[q][3];
          *(float4*)dst = v;
        }
        __syncthreads();
      }
    }
  }
}

// Column sweep: one WG per (class, column j in 0..6).
__global__ __launch_bounds__(256) void colsweep_kernel(float* __restrict__ M,
                                                       short* __restrict__ Wb) {
  __shared__ float TL[64 * 68];
  __shared__ float TW[64 * 68];
  int cls = blockIdx.x / 7;
  int j = blockIdx.x % 7;
  float* Mk = M + (size_t)cls * DD;
  short* Wk = Wb + (size_t)cls * DD;
  int tid = threadIdx.x;
  int ty = tid >> 4, tx = tid & 15;
  int sr = tid >> 2, sq = (tid & 3) << 4;
  for (int i = j + 1; i < 8; ++i) {
    float acc[4][4];
    #pragma unroll
    for (int a = 0; a < 4; ++a)
      #pragma unroll
      for (int b = 0; b < 4; ++b) acc[a][b] = 0.f;
    for (int k = j; k < i; ++k) {
      __syncthreads();
      {
        const float* a = Mk + (size_t)((i << 6) + sr)*DIM + (k << 6) + sq;
        const float* b = Mk + (size_t)((j << 6) + sr)*DIM + (k << 6) + sq;
        #pragma unroll
        for (int t4 = 0; t4 < 4; ++t4) {
          float4 va = *(const float4*)(a + 4*t4);
          TL[(sq+4*t4+0)*68+sr]=va.x; TL[(sq+4*t4+1)*68+sr]=va.y;
          TL[(sq+4*t4+2)*68+sr]=va.z; TL[(sq+4*t4+3)*68+sr]=va.w;
          *(float4*)(TW + sr*68 + sq + 4*t4) = *(const float4*)(b + 4*t4);
        }
      }
      __syncthreads();
      #pragma unroll 16
      for (int m = 0; m < 64; ++m) {
        float4 av = *(const float4*)(TL + m*68 + (ty << 2));
        float4 bv = *(const float4*)(TW + m*68 + (tx << 2));
        float a4[4] = {av.x, av.y, av.z, av.w};
        float b4[4] = {bv.x, bv.y, bv.z, bv.w};
        #pragma unroll
        for (int ir = 0; ir < 4; ++ir)
          #pragma unroll
          for (int ic = 0; ic < 4; ++ic) acc[ir][ic] += a4[ir] * b4[ic];
      }
    }
    __syncthreads();
    #pragma unroll
    for (int q = 0; q < 4; ++q) {
      float4 v; v.x = acc[q][0]; v.y = acc[q][1]; v.z = acc[q][2]; v.w = acc[q][3];
      *(float4*)(TW + ((ty << 2) + q)*68 + (tx << 2)) = v;
    }
    {
      const float* a = Mk + (size_t)((i << 6) + sr)*DIM + (i << 6) + sq;
      #pragma unroll
      for (int t4 = 0; t4 < 4; ++t4) {
        float4 va = *(const float4*)(a + 4*t4);
        TL[(sq+4*t4+0)*68+sr]=va.x; TL[(sq+4*t4+1)*68+sr]=va.y;
        TL[(sq+4*t4+2)*68+sr]=va.z; TL[(sq+4*t4+3)*68+sr]=va.w;
      }
    }
    __syncthreads();
    float r2[4][4];
    #pragma unroll
    for (int a = 0; a < 4; ++a)
      #pragma unroll
      for (int b = 0; b < 4; ++b) r2[a][b] = 0.f;
    #pragma unroll 16
    for (int m = 0; m < 64; ++m) {
      float4 av = *(const float4*)(TL + m*68 + (ty << 2));
      float4 bv = *(const float4*)(TW + m*68 + (tx << 2));
      float a4[4] = {av.x, av.y, av.z, av.w};
      float b4[4] = {bv.x, bv.y, bv.z, bv.w};
      #pragma unroll
      for (int ir = 0; ir < 4; ++ir)
        #pragma unroll
        for (int ic = 0; ic < 4; ++ic) r2[ir][ic] += a4[ir] * b4[ic];
    }
    #pragma unroll
    for (int q = 0; q < 4; ++q) {
      int a = (ty << 2) + q;
      float4 v; v.x = -r2[q][0]; v.y = -r2[q][1]; v.z = -r2[q][2]; v.w = -r2[q][3];
      *(float4*)(Mk + (size_t)((j << 6) + a)*DIM + (i << 6) + (tx << 2)) = v;
      s16x4 h;
      h[0] = f2bf(v.x); h[1] = f2bf(v.y); h[2] = f2bf(v.z); h[3] = f2bf(v.w);
      *(s16x4*)(Wk + (size_t)((i << 6) + a)*DIM + (j << 6) + (tx << 2)) = h;
    }
  }
}

// scores via bf16 MFMA. Depth-1 staging pipeline with NO cross-iteration
// register state: per stage, load next W tile -> regs, MFMA current LDS
// buffer, ds_write regs to other buffer, one barrier. A-fragments straight
// from X/mu (f32->bf16) at dc boundaries. jt-paired 32-reg accumulator.
__global__ __launch_bounds__(256) void score_kernel(const float* __restrict__ X,
                                                    const float* __restrict__ muK,
                                                    const float* __restrict__ cK,
                                                    const short* __restrict__ W,
                                                    const float* __restrict__ aux,
                                                    float* __restrict__ out) {
  __shared__ __align__(16) short WBs[2][4096];
  __shared__ float sred[4];
  int bid = blockIdx.x;
  int wg = ((bid & 7) * 400) + (bid >> 3);   // XCD swizzle (3200 = 8*400)
  int kc = wg >> 5;
  int n0 = (wg & 31) << 6;
  int tid = threadIdx.x;
  int lane = tid & 63, wv = tid >> 6;
  int srow = tid >> 2;
  int sc4 = (tid & 3) << 4;
  const short* Wk = W + (size_t)kc * DD;
  const float* mu = muK + (size_t)kc * DIM;
  int r16 = lane & 15;
  int k8 = (lane >> 4) << 3;
  int arow = (wv << 4) + r16;
  int sb0 = ((srow << 7) + (sc4 << 1)) ^ ((srow & 7) << 4);
  int sb1 = ((srow << 7) + (sc4 << 1) + 16) ^ ((srow & 7) << 4);

  // schedule: group g covers jt in {2g,2g+1}; dc-outer within group.
  constexpr int SJT[36] = {0,1,1, 2,3,2,3,2,3,3, 4,5,4,5,4,5,4,5,4,5,5,
                           6,7,6,7,6,7,6,7,6,7,6,7,6,7,7};
  constexpr int SDC[36] = {0,0,1, 0,0,1,1,2,2,3, 0,0,1,1,2,2,3,3,4,4,5,
                           0,0,1,1,2,2,3,3,4,4,5,5,6,6,7};

  // prologue: W tile (0,0) -> WBs[0]; sum(cK)
  {
    const uint4* pp = (const uint4*)(Wk + (size_t)srow*DIM + sc4);
    uint4 t0 = pp[0], t1 = pp[1];
    *(uint4*)((char*)WBs[0] + sb0) = t0;
    *(uint4*)((char*)WBs[0] + sb1) = t1;
  }
  {
    float v = (tid < NCLS) ? cK[tid] : 0.f;
    #pragma unroll
    for (int o = 32; o > 0; o >>= 1) v += __shfl_xor(v, o);
    if (lane == 0) sred[wv] = v;
  }
  __syncthreads();
  float sumck = sred[0] + sred[1] + sred[2] + sred[3];

  float qp[4] = {0.f, 0.f, 0.f, 0.f};
  f32x4 acc[2][4];
  #pragma unroll
  for (int a = 0; a < 2; ++a)
    #pragma unroll
    for (int jj = 0; jj < 4; ++jj) { acc[a][jj][0]=0.f; acc[a][jj][1]=0.f; acc[a][jj][2]=0.f; acc[a][jj][3]=0.f; }
  bf16x8 af0, af1;

  #pragma unroll
  for (int s = 0; s < 36; ++s) {
    const int jt = SJT[s], dc = SDC[s];
    // issue next W tile load (lives only within this stage)
    uint4 t0, t1;
    const bool more = (s + 1 < 36);
    if (more) {
      const uint4* pp = (const uint4*)(Wk + (size_t)((SJT[s+1] << 6) + srow)*DIM +
                                       (SDC[s+1] << 6) + sc4);
      t0 = pp[0]; t1 = pp[1];
    }
    // A fragments: reload when dc changes
    if (s == 0 || SDC[s-1] != dc) {
      int col = (dc << 6) + k8;
      const float* xp = X + (size_t)(n0 + arow)*DIM + col;
      float4 x0 = *(const float4*)xp;
      float4 x1 = *(const float4*)(xp + 4);
      float4 m0 = *(const float4*)(mu + col);
      float4 m1 = *(const float4*)(mu + col + 4);
      af0[0]=f2bf(x0.x-m0.x); af0[1]=f2bf(x0.y-m0.y); af0[2]=f2bf(x0.z-m0.z); af0[3]=f2bf(x0.w-m0.w);
      af0[4]=f2bf(x1.x-m1.x); af0[5]=f2bf(x1.y-m1.y); af0[6]=f2bf(x1.z-m1.z); af0[7]=f2bf(x1.w-m1.w);
      float4 x2 = *(const float4*)(xp + 32);
      float4 x3 = *(const float4*)(xp + 36);
      float4 m2 = *(const float4*)(mu + col + 32);
      float4 m3 = *(const float4*)(mu + col + 36);
      af1[0]=f2bf(x2.x-m2.x); af1[1]=f2bf(x2.y-m2.y); af1[2]=f2bf(x2.z-m2.z); af1[3]=f2bf(x2.w-m2.w);
      af1[4]=f2bf(x3.x-m3.x); af1[5]=f2bf(x3.y-m3.y); af1[6]=f2bf(x3.z-m3.z); af1[7]=f2bf(x3.w-m3.w);
    }
    __builtin_amdgcn_s_setprio(1);
    #pragma unroll
    for (int ks = 0; ks < 2; ++ks) {
      bf16x8 afk = ks ? af1 : af0;
      #pragma unroll
      for (int jj = 0; jj < 4; ++jj) {
        int brow = (jj << 4) + r16;
        bf16x8 bfr = *(const bf16x8*)((const char*)WBs[s & 1] +
                     (((brow << 7) + (((ks << 5) + k8) << 1)) ^ ((brow & 7) << 4)));
        acc[jt & 1][jj] = __builtin_amdgcn_mfma_f32_16x16x32_bf16(afk, bfr, acc[jt & 1][jj], 0, 0, 0);
      }
    }
    __builtin_amdgcn_s_setprio(0);
    if (more) {   // write next tile into the other buffer
      *(uint4*)((char*)WBs[(s+1) & 1] + sb0) = t0;
      *(uint4*)((char*)WBs[(s+1) & 1] + sb1) = t1;
    }
    __syncthreads();
    if (s == 2 || s == 9 || s == 20 || s == 35) {   // group end: square & reset
      #pragma unroll
      for (int a = 0; a < 2; ++a)
        #pragma unroll
        for (int jj = 0; jj < 4; ++jj)
          #pragma unroll
          for (int r = 0; r < 4; ++r) {
            float y = acc[a][jj][r]; qp[r] += y * y;
            acc[a][jj][r] = 0.f;
          }
    }
  }
  #pragma unroll
  for (int r = 0; r < 4; ++r) {
    qp[r] += __shfl_xor(qp[r], 1);
    qp[r] += __shfl_xor(qp[r], 2);
    qp[r] += __shfl_xor(qp[r], 4);
    qp[r] += __shfl_xor(qp[r], 8);
  }
  float ck = cK[kc];
  float base;
  if (ck == 0.f) base = -INFINITY;
  else base = logf(ck) - logf(sumck) - 0.25f * logf(aux[1 + kc]);
  if ((lane & 15) == 0) {
    int nbase = n0 + (wv << 4) + ((lane >> 4) << 2);
    #pragma unroll
    for (int r = 0; r < 4; ++r)
      out[(size_t)(nbase + r)*NCLS + kc] = base - 0.5f * qp[r];
  }
}

extern "C" void kernel_launch(void* const* d_in, const int* in_sizes, int n_in,
                              void* d_out, int out_size, void* d_ws, size_t ws_size,
                              hipStream_t stream) {
  (void)in_sizes; (void)n_in; (void)out_size; (void)ws_size;
  const float* X      = (const float*)d_in[0];
  const float* muK    = (const float*)d_in[1];
  const float* SigmaK = (const float*)d_in[2];
  const float* Sigma  = (const float*)d_in[3];
  const float* cK     = (const float*)d_in[4];
  float* out = (float*)d_out;
  char* ws = (char*)d_ws;
  float* M   = (float*)ws;                                   // 104857600 B
  short* W   = (short*)(ws + (size_t)NCLS * DD * 4);         //  52428800 B
  float* aux = (float*)(ws + (size_t)NCLS * DD * 6);         //       404 B

  hipMemsetAsync(aux, 0, (1 + NCLS) * sizeof(float), stream);
  prep_kernel<<<400, 256, 0, stream>>>(SigmaK, Sigma, M, aux);
  for (int p = 0; p < 4; ++p) {
    fdt_kernel<<<NCLS, 256, 0, stream>>>(M, W, p);
    int n = 7 - p;
    syrk_kernel<<<NCLS * (n * (n + 1) / 2), 256, 0, stream>>>(M, p);
  }
  tail_kernel<<<NCLS, 256, 0, stream>>>(M, W);
  colsweep_kernel<<<NCLS * 7, 256, 0, stream>>>(M, W);
  score_kernel<<<NCLS * 32, 256, 0, stream>>>(X, muK, cK, W, aux, out);
}

// Round 8
// 879.555 us; speedup vs baseline: 1.3687x; 1.2631x over previous
//
#include <hip/hip_runtime.h>
#include <math.h>

#define DIM 512
#define NCLS 100
#define NS 2048
#define DD (DIM*DIM)
#define SHRINKV 1e-4f

typedef short bf16x8 __attribute__((ext_vector_type(8)));
typedef short s16x4 __attribute__((ext_vector_type(4)));
typedef float f32x4 __attribute__((ext_vector_type(4)));

static __device__ __forceinline__ short f2bf(float f) {
  unsigned int u = __float_as_uint(f);
  u += 0x7FFFu + ((u >> 16) & 1u);   // round-to-nearest-even
  return (short)(u >> 16);
}

// Build M_k = (1-sh)*(0.5*(SigmaK_k+Sigma)) + sh*I ; accumulate ||RegSigma||_F^2
__global__ __launch_bounds__(256) void prep_kernel(const float* __restrict__ SigmaK,
                                                   const float* __restrict__ Sigma,
                                                   float* __restrict__ M,
                                                   float* __restrict__ aux) {
  int b = blockIdx.x;
  int k = b >> 2, chunk = b & 3;
  const float* Sk = SigmaK + (size_t)k * DD;
  float* Mk = M + (size_t)k * DD;
  int base0 = chunk << 16;
  float fro = 0.f;
  const float oms = 1.0f - SHRINKV;
  for (int it = 0; it < 64; ++it) {
    int idx = base0 + (it << 10) + (threadIdx.x << 2);
    float4 a = *(const float4*)(Sk + idx);
    float4 g = *(const float4*)(Sigma + idx);
    int r = idx >> 9, c = idx & 511;
    float4 reg;
    reg.x = 0.5f*(a.x + g.x); reg.y = 0.5f*(a.y + g.y);
    reg.z = 0.5f*(a.z + g.z); reg.w = 0.5f*(a.w + g.w);
    fro += reg.x*reg.x + reg.y*reg.y + reg.z*reg.z + reg.w*reg.w;
    float4 m;
    m.x = oms*reg.x + ((r == c + 0) ? SHRINKV : 0.f);
    m.y = oms*reg.y + ((r == c + 1) ? SHRINKV : 0.f);
    m.z = oms*reg.z + ((r == c + 2) ? SHRINKV : 0.f);
    m.w = oms*reg.w + ((r == c + 3) ? SHRINKV : 0.f);
    *(float4*)(Mk + idx) = m;
  }
  __shared__ float red[4];
  int lane = threadIdx.x & 63, w = threadIdx.x >> 6;
  for (int o = 32; o > 0; o >>= 1) fro += __shfl_down(fro, o);
  if (lane == 0) red[w] = fro;
  __syncthreads();
  if (threadIdx.x == 0) atomicAdd(&aux[1 + k], red[0] + red[1] + red[2] + red[3]);
}

// Fused fdiag + trsm for panel p. One 256-thread WG per class.
__global__ __launch_bounds__(256) void fdt_kernel(float* __restrict__ M,
                                                  short* __restrict__ Wb, int p) {
  __shared__ float Llds[64 * 68];
  __shared__ float invT[64 * 68];
  __shared__ float TA[64 * 68];
  int kcls = blockIdx.x;
  float* Mk = M + (size_t)kcls * DD;
  short* Wk = Wb + (size_t)kcls * DD;
  int tid = threadIdx.x, lane = tid & 63, wv = tid >> 6;
  int ty = tid >> 4, tx = tid & 15;
  int sr = tid >> 2, sq = (tid & 3) << 4;
  int p0 = p << 6;
  if (wv == 0) {
    float row[64];
    const float* src = Mk + (size_t)(p0 + lane) * DIM + p0;
    #pragma unroll
    for (int c4 = 0; c4 < 64; c4 += 4) {
      float4 v = *(const float4*)(src + c4);
      row[c4] = v.x; row[c4+1] = v.y; row[c4+2] = v.z; row[c4+3] = v.w;
    }
    #pragma unroll
    for (int j = 0; j < 64; ++j) {
      float diagv = __shfl(row[j], j);
      float dv = sqrtf(diagv);
      float rinv = 1.0f / dv;
      float myLj = row[j] * rinv;
      row[j] = myLj;
      #pragma unroll
      for (int c = j + 1; c < 64; ++c)
        row[c] = fmaf(-myLj, __shfl(myLj, c), row[c]);
    }
    #pragma unroll
    for (int c = 0; c < 64; ++c)
      Llds[lane * 68 + c] = (c <= lane) ? row[c] : 0.f;
  }
  __syncthreads();
  if (wv == 0) {
    float w[64];   // lane holds column `lane` of inv: w[r] = inv[r][lane]
    #pragma unroll
    for (int r = 0; r < 64; ++r) {
      float s = 0.f;
      #pragma unroll
      for (int kk = 0; kk + 4 <= r; kk += 4) {
        float4 lv = *(const float4*)(Llds + r*68 + kk);
        s += lv.x*w[kk] + lv.y*w[kk+1] + lv.z*w[kk+2] + lv.w*w[kk+3];
      }
      #pragma unroll
      for (int kk = r & ~3; kk < r; ++kk) s += Llds[r*68 + kk] * w[kk];
      float rhs = ((r == lane) ? 1.0f : 0.0f) - s;
      w[r] = rhs / Llds[r*68 + r];   // exact 0 for r < lane
    }
    #pragma unroll
    for (int r = 0; r < 64; ++r) {
      Mk[(size_t)(p0 + r)*DIM + p0 + lane] = w[r];
      Wk[(size_t)(p0 + r)*DIM + p0 + lane] = f2bf(w[r]);
      invT[lane*68 + r] = w[r];   // invT[m][c] = inv[c][m]
    }
  }
  __syncthreads();
  for (int i = p + 1; i < 8; ++i) {
    {
      const float* a = Mk + (size_t)((i << 6) + sr)*DIM + p0 + sq;
      #pragma unroll
      for (int t4 = 0; t4 < 4; ++t4) {
        float4 va = *(const float4*)(a + 4*t4);
        TA[(sq+4*t4+0)*68+sr]=va.x; TA[(sq+4*t4+1)*68+sr]=va.y;
        TA[(sq+4*t4+2)*68+sr]=va.z; TA[(sq+4*t4+3)*68+sr]=va.w;
      }
    }
    __syncthreads();
    float acc[4][4];
    #pragma unroll
    for (int a2 = 0; a2 < 4; ++a2)
      #pragma unroll
      for (int b2 = 0; b2 < 4; ++b2) acc[a2][b2] = 0.f;
    #pragma unroll 16
    for (int m = 0; m < 64; ++m) {
      float4 av = *(const float4*)(TA + m*68 + (ty << 2));
      float4 bv = *(const float4*)(invT + m*68 + (tx << 2));
      float a4[4] = {av.x, av.y, av.z, av.w};
      float b4[4] = {bv.x, bv.y, bv.z, bv.w};
      #pragma unroll
      for (int ir = 0; ir < 4; ++ir)
        #pragma unroll
        for (int ic = 0; ic < 4; ++ic) acc[ir][ic] += a4[ir] * b4[ic];
    }
    #pragma unroll
    for (int q = 0; q < 4; ++q) {
      float4 v; v.x = acc[q][0]; v.y = acc[q][1]; v.z = acc[q][2]; v.w = acc[q][3];
      *(float4*)(Mk + (size_t)((i << 6) + (ty << 2) + q)*DIM + p0 + (tx << 2)) = v;
    }
    __syncthreads();   // TA reusable next iteration
  }
}

// SYRK: for p < j <= i, A_ij -= L_ip * L_jp^T. One WG per (class, pair).
__global__ __launch_bounds__(256) void syrk_kernel(float* __restrict__ M, int p) {
  __shared__ float TA[64 * 68];
  __shared__ float TB[64 * 68];
  int n = 7 - p;
  int T = n * (n + 1) / 2;
  int cls = blockIdx.x / T;
  int t = blockIdx.x % T;
  int bi = 0;
  while (t > bi) { t -= bi + 1; ++bi; }
  int i = p + 1 + bi, j = p + 1 + t;
  float* Mk = M + (size_t)cls * DD;
  int tid = threadIdx.x;
  int ty = tid >> 4, tx = tid & 15;
  int sr = tid >> 2, sq = (tid & 3) << 4;
  {
    const float* a = Mk + (size_t)((i << 6) + sr)*DIM + (p << 6) + sq;
    const float* b = Mk + (size_t)((j << 6) + sr)*DIM + (p << 6) + sq;
    #pragma unroll
    for (int t4 = 0; t4 < 4; ++t4) {
      float4 va = *(const float4*)(a + 4*t4);
      TA[(sq+4*t4+0)*68+sr]=va.x; TA[(sq+4*t4+1)*68+sr]=va.y;
      TA[(sq+4*t4+2)*68+sr]=va.z; TA[(sq+4*t4+3)*68+sr]=va.w;
      float4 vb = *(const float4*)(b + 4*t4);
      TB[(sq+4*t4+0)*68+sr]=vb.x; TB[(sq+4*t4+1)*68+sr]=vb.y;
      TB[(sq+4*t4+2)*68+sr]=vb.z; TB[(sq+4*t4+3)*68+sr]=vb.w;
    }
  }
  __syncthreads();
  float acc[4][4];
  #pragma unroll
  for (int a = 0; a < 4; ++a)
    #pragma unroll
    for (int b = 0; b < 4; ++b) acc[a][b] = 0.f;
  #pragma unroll 16
  for (int m = 0; m < 64; ++m) {
    float4 av = *(const float4*)(TA + m*68 + (ty << 2));
    float4 bv = *(const float4*)(TB + m*68 + (tx << 2));
    float a4[4] = {av.x, av.y, av.z, av.w};
    float b4[4] = {bv.x, bv.y, bv.z, bv.w};
    #pragma unroll
    for (int ir = 0; ir < 4; ++ir)
      #pragma unroll
      for (int ic = 0; ic < 4; ++ic) acc[ir][ic] += a4[ir] * b4[ic];
  }
  #pragma unroll
  for (int q = 0; q < 4; ++q) {
    float* dst = Mk + (size_t)((i << 6) + (ty << 2) + q)*DIM + (j << 6) + (tx << 2);
    float4 v = *(const float4*)dst;
    v.x -= acc[q][0]; v.y -= acc[q][1]; v.z -= acc[q][2]; v.w -= acc[q][3];
    *(float4*)dst = v;
  }
}

// Tail: panels 4..7 fused per class (fdiag + trsm + syrk in-WG).
__global__ __launch_bounds__(256) void tail_kernel(float* __restrict__ M,
                                                   short* __restrict__ Wb) {
  __shared__ float Llds[64 * 68];
  __shared__ float invT[64 * 68];
  __shared__ float TA[64 * 68];
  __shared__ float TB[64 * 68];
  int kcls = blockIdx.x;
  float* Mk = M + (size_t)kcls * DD;
  short* Wk = Wb + (size_t)kcls * DD;
  int tid = threadIdx.x, lane = tid & 63, wv = tid >> 6;
  int ty = tid >> 4, tx = tid & 15;
  int sr = tid >> 2, sq = (tid & 3) << 4;
  for (int p = 4; p < 8; ++p) {
    int p0 = p << 6;
    __syncthreads();
    if (wv == 0) {
      float row[64];
      const float* src = Mk + (size_t)(p0 + lane) * DIM + p0;
      #pragma unroll
      for (int c4 = 0; c4 < 64; c4 += 4) {
        float4 v = *(const float4*)(src + c4);
        row[c4] = v.x; row[c4+1] = v.y; row[c4+2] = v.z; row[c4+3] = v.w;
      }
      #pragma unroll
      for (int j = 0; j < 64; ++j) {
        float diagv = __shfl(row[j], j);
        float dv = sqrtf(diagv);
        float rinv = 1.0f / dv;
        float myLj = row[j] * rinv;
        row[j] = myLj;
        #pragma unroll
        for (int c = j + 1; c < 64; ++c)
          row[c] = fmaf(-myLj, __shfl(myLj, c), row[c]);
      }
      #pragma unroll
      for (int c = 0; c < 64; ++c)
        Llds[lane * 68 + c] = (c <= lane) ? row[c] : 0.f;
    }
    __syncthreads();
    if (wv == 0) {
      float w[64];
      #pragma unroll
      for (int r = 0; r < 64; ++r) {
        float s = 0.f;
        #pragma unroll
        for (int kk = 0; kk + 4 <= r; kk += 4) {
          float4 lv = *(const float4*)(Llds + r*68 + kk);
          s += lv.x*w[kk] + lv.y*w[kk+1] + lv.z*w[kk+2] + lv.w*w[kk+3];
        }
        #pragma unroll
        for (int kk = r & ~3; kk < r; ++kk) s += Llds[r*68 + kk] * w[kk];
        float rhs = ((r == lane) ? 1.0f : 0.0f) - s;
        w[r] = rhs / Llds[r*68 + r];
      }
      #pragma unroll
      for (int r = 0; r < 64; ++r) {
        Mk[(size_t)(p0 + r)*DIM + p0 + lane] = w[r];
        Wk[(size_t)(p0 + r)*DIM + p0 + lane] = f2bf(w[r]);
        invT[lane*68 + r] = w[r];
      }
    }
    __syncthreads();
    for (int i = p + 1; i < 8; ++i) {
      {
        const float* a = Mk + (size_t)((i << 6) + sr)*DIM + p0 + sq;
        #pragma unroll
        for (int t4 = 0; t4 < 4; ++t4) {
          float4 va = *(const float4*)(a + 4*t4);
          TA[(sq+4*t4+0)*68+sr]=va.x; TA[(sq+4*t4+1)*68+sr]=va.y;
          TA[(sq+4*t4+2)*68+sr]=va.z; TA[(sq+4*t4+3)*68+sr]=va.w;
        }
      }
      __syncthreads();
      float acc[4][4];
      #pragma unroll
      for (int a2 = 0; a2 < 4; ++a2)
        #pragma unroll
        for (int b2 = 0; b2 < 4; ++b2) acc[a2][b2] = 0.f;
      #pragma unroll 16
      for (int m = 0; m < 64; ++m) {
        float4 av = *(const float4*)(TA + m*68 + (ty << 2));
        float4 bv = *(const float4*)(invT + m*68 + (tx << 2));
        float a4[4] = {av.x, av.y, av.z, av.w};
        float b4[4] = {bv.x, bv.y, bv.z, bv.w};
        #pragma unroll
        for (int ir = 0; ir < 4; ++ir)
          #pragma unroll
          for (int ic = 0; ic < 4; ++ic) acc[ir][ic] += a4[ir] * b4[ic];
      }
      #pragma unroll
      for (int q = 0; q < 4; ++q) {
        float4 v; v.x = acc[q][0]; v.y = acc[q][1]; v.z = acc[q][2]; v.w = acc[q][3];
        *(float4*)(Mk + (size_t)((i << 6) + (ty << 2) + q)*DIM + p0 + (tx << 2)) = v;
      }
      __syncthreads();
    }
    for (int i = p + 1; i < 8; ++i) {
      for (int j = p + 1; j <= i; ++j) {
        {
          const float* a = Mk + (size_t)((i << 6) + sr)*DIM + p0 + sq;
          const float* b = Mk + (size_t)((j << 6) + sr)*DIM + p0 + sq;
          #pragma unroll
          for (int t4 = 0; t4 < 4; ++t4) {
            float4 va = *(const float4*)(a + 4*t4);
            TA[(sq+4*t4+0)*68+sr]=va.x; TA[(sq+4*t4+1)*68+sr]=va.y;
            TA[(sq+4*t4+2)*68+sr]=va.z; TA[(sq+4*t4+3)*68+sr]=va.w;
            float4 vb = *(const float4*)(b + 4*t4);
            TB[(sq+4*t4+0)*68+sr]=vb.x; TB[(sq+4*t4+1)*68+sr]=vb.y;
            TB[(sq+4*t4+2)*68+sr]=vb.z; TB[(sq+4*t4+3)*68+sr]=vb.w;
          }
        }
        __syncthreads();
        float acc[4][4];
        #pragma unroll
        for (int a2 = 0; a2 < 4; ++a2)
          #pragma unroll
          for (int b2 = 0; b2 < 4; ++b2) acc[a2][b2] = 0.f;
        #pragma unroll 16
        for (int m = 0; m < 64; ++m) {
          float4 av = *(const float4*)(TA + m*68 + (ty << 2));
          float4 bv = *(const float4*)(TB + m*68 + (tx << 2));
          float a4[4] = {av.x, av.y, av.z, av.w};
          float b4[4] = {bv.x, bv.y, bv.z, bv.w};
          #pragma unroll
          for (int ir = 0; ir < 4; ++ir)
            #pragma unroll
            for (int ic = 0; ic < 4; ++ic) acc[ir][ic] += a4[ir] * b4[ic];
        }
        #pragma unroll
        for (int q = 0; q < 4; ++q) {
          float* dst = Mk + (size_t)((i << 6) + (ty << 2) + q)*DIM + (j << 6) + (tx << 2);
          float4 v = *(const float4*)dst;
          v.x -= acc[q][0]; v.y -= acc[q][1]; v.z -= acc[q][2]; v.w -= acc[q][3];
          *(float4*)dst = v;
        }
        __syncthreads();
      }
    }
  }
}

// Column sweep: one WG per (class, column j in 0..6).
__global__ __launch_bounds__(256) void colsweep_kernel(float* __restrict__ M,
                                                       short* __restrict__ Wb) {
  __shared__ float TL[64 * 68];
  __shared__ float TW[64 * 68];
  int cls = blockIdx.x / 7;
  int j = blockIdx.x % 7;
  float* Mk = M + (size_t)cls * DD;
  short* Wk = Wb + (size_t)cls * DD;
  int tid = threadIdx.x;
  int ty = tid >> 4, tx = tid & 15;
  int sr = tid >> 2, sq = (tid & 3) << 4;
  for (int i = j + 1; i < 8; ++i) {
    float acc[4][4];
    #pragma unroll
    for (int a = 0; a < 4; ++a)
      #pragma unroll
      for (int b = 0; b < 4; ++b) acc[a][b] = 0.f;
    for (int k = j; k < i; ++k) {
      __syncthreads();
      {
        const float* a = Mk + (size_t)((i << 6) + sr)*DIM + (k << 6) + sq;
        const float* b = Mk + (size_t)((j << 6) + sr)*DIM + (k << 6) + sq;
        #pragma unroll
        for (int t4 = 0; t4 < 4; ++t4) {
          float4 va = *(const float4*)(a + 4*t4);
          TL[(sq+4*t4+0)*68+sr]=va.x; TL[(sq+4*t4+1)*68+sr]=va.y;
          TL[(sq+4*t4+2)*68+sr]=va.z; TL[(sq+4*t4+3)*68+sr]=va.w;
          *(float4*)(TW + sr*68 + sq + 4*t4) = *(const float4*)(b + 4*t4);
        }
      }
      __syncthreads();
      #pragma unroll 16
      for (int m = 0; m < 64; ++m) {
        float4 av = *(const float4*)(TL + m*68 + (ty << 2));
        float4 bv = *(const float4*)(TW + m*68 + (tx << 2));
        float a4[4] = {av.x, av.y, av.z, av.w};
        float b4[4] = {bv.x, bv.y, bv.z, bv.w};
        #pragma unroll
        for (int ir = 0; ir < 4; ++ir)
          #pragma unroll
          for (int ic = 0; ic < 4; ++ic) acc[ir][ic] += a4[ir] * b4[ic];
      }
    }
    __syncthreads();
    #pragma unroll
    for (int q = 0; q < 4; ++q) {
      float4 v; v.x = acc[q][0]; v.y = acc[q][1]; v.z = acc[q][2]; v.w = acc[q][3];
      *(float4*)(TW + ((ty << 2) + q)*68 + (tx << 2)) = v;
    }
    {
      const float* a = Mk + (size_t)((i << 6) + sr)*DIM + (i << 6) + sq;
      #pragma unroll
      for (int t4 = 0; t4 < 4; ++t4) {
        float4 va = *(const float4*)(a + 4*t4);
        TL[(sq+4*t4+0)*68+sr]=va.x; TL[(sq+4*t4+1)*68+sr]=va.y;
        TL[(sq+4*t4+2)*68+sr]=va.z; TL[(sq+4*t4+3)*68+sr]=va.w;
      }
    }
    __syncthreads();
    float r2[4][4];
    #pragma unroll
    for (int a = 0; a < 4; ++a)
      #pragma unroll
      for (int b = 0; b < 4; ++b) r2[a][b] = 0.f;
    #pragma unroll 16
    for (int m = 0; m < 64; ++m) {
      float4 av = *(const float4*)(TL + m*68 + (ty << 2));
      float4 bv = *(const float4*)(TW + m*68 + (tx << 2));
      float a4[4] = {av.x, av.y, av.z, av.w};
      float b4[4] = {bv.x, bv.y, bv.z, bv.w};
      #pragma unroll
      for (int ir = 0; ir < 4; ++ir)
        #pragma unroll
        for (int ic = 0; ic < 4; ++ic) r2[ir][ic] += a4[ir] * b4[ic];
    }
    #pragma unroll
    for (int q = 0; q < 4; ++q) {
      int a = (ty << 2) + q;
      float4 v; v.x = -r2[q][0]; v.y = -r2[q][1]; v.z = -r2[q][2]; v.w = -r2[q][3];
      *(float4*)(Mk + (size_t)((j << 6) + a)*DIM + (i << 6) + (tx << 2)) = v;
      s16x4 h;
      h[0] = f2bf(v.x); h[1] = f2bf(v.y); h[2] = f2bf(v.z); h[3] = f2bf(v.w);
      *(s16x4*)(Wk + (size_t)((i << 6) + a)*DIM + (j << 6) + (tx << 2)) = h;
    }
  }
}

// scores via bf16 MFMA. W tiles staged via global_load_lds into a 4-buffer
// ring, depth-2 pipeline with counted vmcnt + raw barriers (T3+T4). LDS stays
// linear; the reader's XOR swizzle is realized by pre-swizzling the per-lane
// GLOBAL source address (m173 pattern). A-fragments hoisted to prologue so
// the loop's vmcnt stream contains only the staging loads.
__global__ __launch_bounds__(256) void score_kernel(const float* __restrict__ X,
                                                    const float* __restrict__ muK,
                                                    const float* __restrict__ cK,
                                                    const short* __restrict__ W,
                                                    const float* __restrict__ aux,
                                                    float* __restrict__ out) {
  __shared__ __align__(16) char WB4[4][8192];
  __shared__ float sred[4];
  int bid = blockIdx.x;
  int wg = ((bid & 7) * 400) + (bid >> 3);   // XCD swizzle (3200 = 8*400)
  int kc = wg >> 5;
  int n0 = (wg & 31) << 6;
  int tid = threadIdx.x;
  int lane = tid & 63, wv = tid >> 6;
  const short* Wk = W + (size_t)kc * DD;
  const float* mu = muK + (size_t)kc * DIM;
  int r16 = lane & 15;
  int k8 = (lane >> 4) << 3;
  int arow = (wv << 4) + r16;

  // staging lane geometry: instr q covers LDS rows q*32+wv*8 .. +7 (linear),
  // lane l -> row q*32+wv*8+(l>>3), swizzled source col ((l&7)^(l>>3))*8 elems
  int lrow = lane >> 3;
  int lcolel = ((lane & 7) ^ lrow) << 3;

  constexpr int SJT[36] = {0,1,1, 2,3,2,3,2,3,3, 4,5,4,5,4,5,4,5,4,5,5,
                           6,7,6,7,6,7,6,7,6,7,6,7,6,7,7};
  constexpr int SDC[36] = {0,0,1, 0,0,1,1,2,2,3, 0,0,1,1,2,2,3,3,4,4,5,
                           0,0,1,1,2,2,3,3,4,4,5,5,6,6,7};

  // A fragments (diff in bf16): af[dc][ks], computed once (64 VGPR)
  bf16x8 af[8][2];
  #pragma unroll
  for (int dc = 0; dc < 8; ++dc) {
    #pragma unroll
    for (int ks = 0; ks < 2; ++ks) {
      int col = (dc << 6) + (ks << 5) + k8;
      const float* xp = X + (size_t)(n0 + arow)*DIM + col;
      float4 x0 = *(const float4*)xp;
      float4 x1 = *(const float4*)(xp + 4);
      float4 m0 = *(const float4*)(mu + col);
      float4 m1 = *(const float4*)(mu + col + 4);
      bf16x8 h;
      h[0]=f2bf(x0.x-m0.x); h[1]=f2bf(x0.y-m0.y); h[2]=f2bf(x0.z-m0.z); h[3]=f2bf(x0.w-m0.w);
      h[4]=f2bf(x1.x-m1.x); h[5]=f2bf(x1.y-m1.y); h[6]=f2bf(x1.z-m1.z); h[7]=f2bf(x1.w-m1.w);
      af[dc][ks] = h;
    }
  }

  // async stage of W tile for schedule slot s into ring buffer s&3
  auto issue = [&](int s) {
    const int b = s & 3;
    const int rbase = SJT[s] << 6;
    const int cc = (SDC[s] << 6) + lcolel;
    #pragma unroll
    for (int q = 0; q < 2; ++q) {
      const short* g = Wk + (size_t)(rbase + (q << 5) + (wv << 3) + lrow)*DIM + cc;
      __builtin_amdgcn_global_load_lds(
          (const __attribute__((address_space(1))) void*)g,
          (__attribute__((address_space(3))) void*)(WB4[b] + (q << 12) + (wv << 10)),
          16, 0, 0);
    }
  };

  float qp[4] = {0.f, 0.f, 0.f, 0.f};
  f32x4 acc[2][4];
  #pragma unroll
  for (int a = 0; a < 2; ++a)
    #pragma unroll
    for (int jj = 0; jj < 4; ++jj) { acc[a][jj][0]=0.f; acc[a][jj][1]=0.f; acc[a][jj][2]=0.f; acc[a][jj][3]=0.f; }

  issue(0);
  issue(1);
  #pragma unroll
  for (int s = 0; s < 36; ++s) {
    const int jt = SJT[s], dc = SDC[s];
    if (s + 2 < 36) issue(s + 2);   // overwrites buf[(s-2)&3]; ordered by the
                                    // barrier in iteration s-1 (all waves past
                                    // MFMA(s-2) before any wave issues here)
    if (s < 34)      asm volatile("s_waitcnt vmcnt(4)" ::: "memory");
    else if (s == 34) asm volatile("s_waitcnt vmcnt(2)" ::: "memory");
    else              asm volatile("s_waitcnt vmcnt(0)" ::: "memory");
    __builtin_amdgcn_s_barrier();        // all waves' stage-s tile visible
    __builtin_amdgcn_sched_barrier(0);   // rule 18: no ds_read hoisting
    __builtin_amdgcn_s_setprio(1);
    #pragma unroll
    for (int ks = 0; ks < 2; ++ks) {
      #pragma unroll
      for (int jj = 0; jj < 4; ++jj) {
        int brow = (jj << 4) + r16;
        bf16x8 bfr = *(const bf16x8*)((const char*)WB4[s & 3] +
                     (((brow << 7) + (((ks << 5) + k8) << 1)) ^ ((brow & 7) << 4)));
        acc[jt & 1][jj] = __builtin_amdgcn_mfma_f32_16x16x32_bf16(af[dc][ks], bfr, acc[jt & 1][jj], 0, 0, 0);
      }
    }
    __builtin_amdgcn_s_setprio(0);
    if (s == 2 || s == 9 || s == 20 || s == 35) {   // group end: square & reset
      #pragma unroll
      for (int a = 0; a < 2; ++a)
        #pragma unroll
        for (int jj = 0; jj < 4; ++jj)
          #pragma unroll
          for (int r = 0; r < 4; ++r) {
            float y = acc[a][jj][r]; qp[r] += y * y;
            acc[a][jj][r] = 0.f;
          }
    }
  }
  #pragma unroll
  for (int r = 0; r < 4; ++r) {
    qp[r] += __shfl_xor(qp[r], 1);
    qp[r] += __shfl_xor(qp[r], 2);
    qp[r] += __shfl_xor(qp[r], 4);
    qp[r] += __shfl_xor(qp[r], 8);
  }
  // sum(cK) after the pipeline (its __syncthreads would drain vmcnt mid-loop)
  {
    float v = (tid < NCLS) ? cK[tid] : 0.f;
    #pragma unroll
    for (int o = 32; o > 0; o >>= 1) v += __shfl_xor(v, o);
    if (lane == 0) sred[wv] = v;
  }
  __syncthreads();
  float sumck = sred[0] + sred[1] + sred[2] + sred[3];
  float ck = cK[kc];
  float base;
  if (ck == 0.f) base = -INFINITY;
  else base = logf(ck) - logf(sumck) - 0.25f * logf(aux[1 + kc]);
  if ((lane & 15) == 0) {
    int nbase = n0 + (wv << 4) + ((lane >> 4) << 2);
    #pragma unroll
    for (int r = 0; r < 4; ++r)
      out[(size_t)(nbase + r)*NCLS + kc] = base - 0.5f * qp[r];
  }
}

extern "C" void kernel_launch(void* const* d_in, const int* in_sizes, int n_in,
                              void* d_out, int out_size, void* d_ws, size_t ws_size,
                              hipStream_t stream) {
  (void)in_sizes; (void)n_in; (void)out_size; (void)ws_size;
  const float* X      = (const float*)d_in[0];
  const float* muK    = (const float*)d_in[1];
  const float* SigmaK = (const float*)d_in[2];
  const float* Sigma  = (const float*)d_in[3];
  const float* cK     = (const float*)d_in[4];
  float* out = (float*)d_out;
  char* ws = (char*)d_ws;
  float* M   = (float*)ws;                                   // 104857600 B
  short* W   = (short*)(ws + (size_t)NCLS * DD * 4);         //  52428800 B
  float* aux = (float*)(ws + (size_t)NCLS * DD * 6);         //       404 B

  hipMemsetAsync(aux, 0, (1 + NCLS) * sizeof(float), stream);
  prep_kernel<<<400, 256, 0, stream>>>(SigmaK, Sigma, M, aux);
  for (int p = 0; p < 4; ++p) {
    fdt_kernel<<<NCLS, 256, 0, stream>>>(M, W, p);
    int n = 7 - p;
    syrk_kernel<<<NCLS * (n * (n + 1) / 2), 256, 0, stream>>>(M, p);
  }
  tail_kernel<<<NCLS, 256, 0, stream>>>(M, W);
  colsweep_kernel<<<NCLS * 7, 256, 0, stream>>>(M, W);
  score_kernel<<<NCLS * 32, 256, 0, stream>>>(X, muK, cK, W, aux, out);
}

// Round 9
// 871.172 us; speedup vs baseline: 1.3819x; 1.0096x over previous
//
#include <hip/hip_runtime.h>
#include <math.h>

#define DIM 512
#define NCLS 100
#define NS 2048
#define DD (DIM*DIM)
#define SHRINKV 1e-4f

typedef short bf16x8 __attribute__((ext_vector_type(8)));
typedef short s16x4 __attribute__((ext_vector_type(4)));
typedef float f32x4 __attribute__((ext_vector_type(4)));

static __device__ __forceinline__ short f2bf(float f) {
  unsigned int u = __float_as_uint(f);
  u += 0x7FFFu + ((u >> 16) & 1u);   // round-to-nearest-even
  return (short)(u >> 16);
}

// Build M_k = (1-sh)*(0.5*(SigmaK_k+Sigma)) + sh*I ; accumulate ||RegSigma||_F^2
__global__ __launch_bounds__(256) void prep_kernel(const float* __restrict__ SigmaK,
                                                   const float* __restrict__ Sigma,
                                                   float* __restrict__ M,
                                                   float* __restrict__ aux) {
  int b = blockIdx.x;
  int k = b >> 2, chunk = b & 3;
  const float* Sk = SigmaK + (size_t)k * DD;
  float* Mk = M + (size_t)k * DD;
  int base0 = chunk << 16;
  float fro = 0.f;
  const float oms = 1.0f - SHRINKV;
  for (int it = 0; it < 64; ++it) {
    int idx = base0 + (it << 10) + (threadIdx.x << 2);
    float4 a = *(const float4*)(Sk + idx);
    float4 g = *(const float4*)(Sigma + idx);
    int r = idx >> 9, c = idx & 511;
    float4 reg;
    reg.x = 0.5f*(a.x + g.x); reg.y = 0.5f*(a.y + g.y);
    reg.z = 0.5f*(a.z + g.z); reg.w = 0.5f*(a.w + g.w);
    fro += reg.x*reg.x + reg.y*reg.y + reg.z*reg.z + reg.w*reg.w;
    float4 m;
    m.x = oms*reg.x + ((r == c + 0) ? SHRINKV : 0.f);
    m.y = oms*reg.y + ((r == c + 1) ? SHRINKV : 0.f);
    m.z = oms*reg.z + ((r == c + 2) ? SHRINKV : 0.f);
    m.w = oms*reg.w + ((r == c + 3) ? SHRINKV : 0.f);
    *(float4*)(Mk + idx) = m;
  }
  __shared__ float red[4];
  int lane = threadIdx.x & 63, w = threadIdx.x >> 6;
  for (int o = 32; o > 0; o >>= 1) fro += __shfl_down(fro, o);
  if (lane == 0) red[w] = fro;
  __syncthreads();
  if (threadIdx.x == 0) atomicAdd(&aux[1 + k], red[0] + red[1] + red[2] + red[3]);
}

// Fused fdiag + trsm for panel p. One 256-thread WG per class.
// Wave 0: shuffle-Cholesky + triangular inverse (invT[m][c]=inv[c][m]).
// Waves 1-3 pre-stage the first TRSM A-block during the solve; the i-loop
// double-buffers TA so stage(i+1) overlaps GEMM(i).
__global__ __launch_bounds__(256) void fdt_kernel(float* __restrict__ M,
                                                  short* __restrict__ Wb, int p) {
  __shared__ float Llds[64 * 68];
  __shared__ float invT[64 * 68];
  __shared__ float TA[2][64 * 68];
  int kcls = blockIdx.x;
  float* Mk = M + (size_t)kcls * DD;
  short* Wk = Wb + (size_t)kcls * DD;
  int tid = threadIdx.x, lane = tid & 63, wv = tid >> 6;
  int ty = tid >> 4, tx = tid & 15;
  int sr = tid >> 2, sq = (tid & 3) << 4;
  int p0 = p << 6;
  if (wv == 0) {
    float row[64];
    const float* src = Mk + (size_t)(p0 + lane) * DIM + p0;
    #pragma unroll
    for (int c4 = 0; c4 < 64; c4 += 4) {
      float4 v = *(const float4*)(src + c4);
      row[c4] = v.x; row[c4+1] = v.y; row[c4+2] = v.z; row[c4+3] = v.w;
    }
    #pragma unroll
    for (int j = 0; j < 64; ++j) {
      float diagv = __shfl(row[j], j);
      float dv = sqrtf(diagv);
      float rinv = 1.0f / dv;
      float myLj = row[j] * rinv;
      row[j] = myLj;
      #pragma unroll
      for (int c = j + 1; c < 64; ++c)
        row[c] = fmaf(-myLj, __shfl(myLj, c), row[c]);
    }
    #pragma unroll
    for (int c = 0; c < 64; ++c)
      Llds[lane * 68 + c] = (c <= lane) ? row[c] : 0.f;
  }
  __syncthreads();
  if (wv == 0) {
    float w[64];   // lane holds column `lane` of inv: w[r] = inv[r][lane]
    #pragma unroll
    for (int r = 0; r < 64; ++r) {
      float s = 0.f;
      #pragma unroll
      for (int kk = 0; kk + 4 <= r; kk += 4) {
        float4 lv = *(const float4*)(Llds + r*68 + kk);
        s += lv.x*w[kk] + lv.y*w[kk+1] + lv.z*w[kk+2] + lv.w*w[kk+3];
      }
      #pragma unroll
      for (int kk = r & ~3; kk < r; ++kk) s += Llds[r*68 + kk] * w[kk];
      float rhs = ((r == lane) ? 1.0f : 0.0f) - s;
      w[r] = rhs / Llds[r*68 + r];   // exact 0 for r < lane
    }
    #pragma unroll
    for (int r = 0; r < 64; ++r) {
      Mk[(size_t)(p0 + r)*DIM + p0 + lane] = w[r];
      Wk[(size_t)(p0 + r)*DIM + p0 + lane] = f2bf(w[r]);
      invT[lane*68 + r] = w[r];   // invT[m][c] = inv[c][m]
    }
  } else if (p < 7) {
    // pre-stage TA[0] = A_{p+1,p} transposed, concurrent with wave0's solve
    int w1 = wv - 1;
    int r0 = (w1 == 0) ? 0 : (w1 == 1 ? 22 : 43);
    int r1 = (w1 == 0) ? 22 : (w1 == 1 ? 43 : 64);
    const float* ab = Mk + ((size_t)((p + 1) << 6)) * DIM + p0;
    for (int row = r0; row < r1; ++row)
      TA[0][lane*68 + row] = ab[(size_t)row * DIM + lane];
  }
  __syncthreads();
  int cur = 0;
  for (int i = p + 1; i < 8; ++i) {
    if (i + 1 < 8) {   // stage next A-block into the other buffer (overlaps GEMM)
      const float* a = Mk + (size_t)(((i + 1) << 6) + sr)*DIM + p0 + sq;
      #pragma unroll
      for (int t4 = 0; t4 < 4; ++t4) {
        float4 va = *(const float4*)(a + 4*t4);
        TA[cur^1][(sq+4*t4+0)*68+sr]=va.x; TA[cur^1][(sq+4*t4+1)*68+sr]=va.y;
        TA[cur^1][(sq+4*t4+2)*68+sr]=va.z; TA[cur^1][(sq+4*t4+3)*68+sr]=va.w;
      }
    }
    float acc[4][4];
    #pragma unroll
    for (int a2 = 0; a2 < 4; ++a2)
      #pragma unroll
      for (int b2 = 0; b2 < 4; ++b2) acc[a2][b2] = 0.f;
    #pragma unroll 16
    for (int m = 0; m < 64; ++m) {
      float4 av = *(const float4*)(TA[cur] + m*68 + (ty << 2));
      float4 bv = *(const float4*)(invT + m*68 + (tx << 2));
      float a4[4] = {av.x, av.y, av.z, av.w};
      float b4[4] = {bv.x, bv.y, bv.z, bv.w};
      #pragma unroll
      for (int ir = 0; ir < 4; ++ir)
        #pragma unroll
        for (int ic = 0; ic < 4; ++ic) acc[ir][ic] += a4[ir] * b4[ic];
    }
    #pragma unroll
    for (int q = 0; q < 4; ++q) {
      float4 v; v.x = acc[q][0]; v.y = acc[q][1]; v.z = acc[q][2]; v.w = acc[q][3];
      *(float4*)(Mk + (size_t)((i << 6) + (ty << 2) + q)*DIM + p0 + (tx << 2)) = v;
    }
    __syncthreads();   // TA[cur^1] writes visible; TA[cur] free
    cur ^= 1;
  }
}

// SYRK: for p < j <= i, A_ij -= L_ip * L_jp^T. One WG per (class, pair).
__global__ __launch_bounds__(256) void syrk_kernel(float* __restrict__ M, int p) {
  __shared__ float TA[64 * 68];
  __shared__ float TB[64 * 68];
  int n = 7 - p;
  int T = n * (n + 1) / 2;
  int cls = blockIdx.x / T;
  int t = blockIdx.x % T;
  int bi = 0;
  while (t > bi) { t -= bi + 1; ++bi; }
  int i = p + 1 + bi, j = p + 1 + t;
  float* Mk = M + (size_t)cls * DD;
  int tid = threadIdx.x;
  int ty = tid >> 4, tx = tid & 15;
  int sr = tid >> 2, sq = (tid & 3) << 4;
  {
    const float* a = Mk + (size_t)((i << 6) + sr)*DIM + (p << 6) + sq;
    const float* b = Mk + (size_t)((j << 6) + sr)*DIM + (p << 6) + sq;
    #pragma unroll
    for (int t4 = 0; t4 < 4; ++t4) {
      float4 va = *(const float4*)(a + 4*t4);
      TA[(sq+4*t4+0)*68+sr]=va.x; TA[(sq+4*t4+1)*68+sr]=va.y;
      TA[(sq+4*t4+2)*68+sr]=va.z; TA[(sq+4*t4+3)*68+sr]=va.w;
      float4 vb = *(const float4*)(b + 4*t4);
      TB[(sq+4*t4+0)*68+sr]=vb.x; TB[(sq+4*t4+1)*68+sr]=vb.y;
      TB[(sq+4*t4+2)*68+sr]=vb.z; TB[(sq+4*t4+3)*68+sr]=vb.w;
    }
  }
  __syncthreads();
  float acc[4][4];
  #pragma unroll
  for (int a = 0; a < 4; ++a)
    #pragma unroll
    for (int b = 0; b < 4; ++b) acc[a][b] = 0.f;
  #pragma unroll 16
  for (int m = 0; m < 64; ++m) {
    float4 av = *(const float4*)(TA + m*68 + (ty << 2));
    float4 bv = *(const float4*)(TB + m*68 + (tx << 2));
    float a4[4] = {av.x, av.y, av.z, av.w};
    float b4[4] = {bv.x, bv.y, bv.z, bv.w};
    #pragma unroll
    for (int ir = 0; ir < 4; ++ir)
      #pragma unroll
      for (int ic = 0; ic < 4; ++ic) acc[ir][ic] += a4[ir] * b4[ic];
  }
  #pragma unroll
  for (int q = 0; q < 4; ++q) {
    float* dst = Mk + (size_t)((i << 6) + (ty << 2) + q)*DIM + (j << 6) + (tx << 2);
    float4 v = *(const float4*)dst;
    v.x -= acc[q][0]; v.y -= acc[q][1]; v.z -= acc[q][2]; v.w -= acc[q][3];
    *(float4*)dst = v;
  }
}

// Column sweep: one WG per (class, column j in 0..6). Double-buffered staging.
__global__ __launch_bounds__(256) void colsweep_kernel(float* __restrict__ M,
                                                       short* __restrict__ Wb) {
  __shared__ float TL[2][64 * 68];
  __shared__ float TW[2][64 * 68];
  int cls = blockIdx.x / 7;
  int j = blockIdx.x % 7;
  float* Mk = M + (size_t)cls * DD;
  short* Wk = Wb + (size_t)cls * DD;
  int tid = threadIdx.x;
  int ty = tid >> 4, tx = tid & 15;
  int sr = tid >> 2, sq = (tid & 3) << 4;
  for (int i = j + 1; i < 8; ++i) {
    auto stageLW = [&](int k, int buf) {
      const float* a = Mk + (size_t)((i << 6) + sr)*DIM + (k << 6) + sq;
      const float* b = Mk + (size_t)((j << 6) + sr)*DIM + (k << 6) + sq;
      #pragma unroll
      for (int t4 = 0; t4 < 4; ++t4) {
        float4 va = *(const float4*)(a + 4*t4);
        TL[buf][(sq+4*t4+0)*68+sr]=va.x; TL[buf][(sq+4*t4+1)*68+sr]=va.y;
        TL[buf][(sq+4*t4+2)*68+sr]=va.z; TL[buf][(sq+4*t4+3)*68+sr]=va.w;
        *(float4*)(TW[buf] + sr*68 + sq + 4*t4) = *(const float4*)(b + 4*t4);
      }
    };
    float acc[4][4];
    #pragma unroll
    for (int a = 0; a < 4; ++a)
      #pragma unroll
      for (int b = 0; b < 4; ++b) acc[a][b] = 0.f;
    stageLW(j, 0);
    __syncthreads();
    int cur = 0;
    for (int k = j; k < i; ++k) {
      if (k + 1 < i) stageLW(k + 1, cur ^ 1);   // overlaps GEMM below
      #pragma unroll 16
      for (int m = 0; m < 64; ++m) {
        float4 av = *(const float4*)(TL[cur] + m*68 + (ty << 2));
        float4 bv = *(const float4*)(TW[cur] + m*68 + (tx << 2));
        float a4[4] = {av.x, av.y, av.z, av.w};
        float b4[4] = {bv.x, bv.y, bv.z, bv.w};
        #pragma unroll
        for (int ir = 0; ir < 4; ++ir)
          #pragma unroll
          for (int ic = 0; ic < 4; ++ic) acc[ir][ic] += a4[ir] * b4[ic];
      }
      __syncthreads();
      cur ^= 1;
    }
    // finalize: S -> TW[0], W_ii^T -> TL[0]
    #pragma unroll
    for (int q = 0; q < 4; ++q) {
      float4 v; v.x = acc[q][0]; v.y = acc[q][1]; v.z = acc[q][2]; v.w = acc[q][3];
      *(float4*)(TW[0] + ((ty << 2) + q)*68 + (tx << 2)) = v;
    }
    {
      const float* a = Mk + (size_t)((i << 6) + sr)*DIM + (i << 6) + sq;
      #pragma unroll
      for (int t4 = 0; t4 < 4; ++t4) {
        float4 va = *(const float4*)(a + 4*t4);
        TL[0][(sq+4*t4+0)*68+sr]=va.x; TL[0][(sq+4*t4+1)*68+sr]=va.y;
        TL[0][(sq+4*t4+2)*68+sr]=va.z; TL[0][(sq+4*t4+3)*68+sr]=va.w;
      }
    }
    __syncthreads();
    float r2[4][4];
    #pragma unroll
    for (int a = 0; a < 4; ++a)
      #pragma unroll
      for (int b = 0; b < 4; ++b) r2[a][b] = 0.f;
    #pragma unroll 16
    for (int m = 0; m < 64; ++m) {
      float4 av = *(const float4*)(TL[0] + m*68 + (ty << 2));
      float4 bv = *(const float4*)(TW[0] + m*68 + (tx << 2));
      float a4[4] = {av.x, av.y, av.z, av.w};
      float b4[4] = {bv.x, bv.y, bv.z, bv.w};
      #pragma unroll
      for (int ir = 0; ir < 4; ++ir)
        #pragma unroll
        for (int ic = 0; ic < 4; ++ic) r2[ir][ic] += a4[ir] * b4[ic];
    }
    #pragma unroll
    for (int q = 0; q < 4; ++q) {
      int a = (ty << 2) + q;
      float4 v; v.x = -r2[q][0]; v.y = -r2[q][1]; v.z = -r2[q][2]; v.w = -r2[q][3];
      *(float4*)(Mk + (size_t)((j << 6) + a)*DIM + (i << 6) + (tx << 2)) = v;
      s16x4 h;
      h[0] = f2bf(v.x); h[1] = f2bf(v.y); h[2] = f2bf(v.z); h[3] = f2bf(v.w);
      *(s16x4*)(Wk + (size_t)((i << 6) + a)*DIM + (j << 6) + (tx << 2)) = h;
    }
    __syncthreads();   // buffers free for next i
  }
}

// scores via bf16 MFMA. W tiles staged via global_load_lds into a 4-buffer
// ring, depth-2 pipeline with counted vmcnt + raw barriers (T3+T4).
__global__ __launch_bounds__(256) void score_kernel(const float* __restrict__ X,
                                                    const float* __restrict__ muK,
                                                    const float* __restrict__ cK,
                                                    const short* __restrict__ W,
                                                    const float* __restrict__ aux,
                                                    float* __restrict__ out) {
  __shared__ __align__(16) char WB4[4][8192];
  __shared__ float sred[4];
  int bid = blockIdx.x;
  int wg = ((bid & 7) * 400) + (bid >> 3);   // XCD swizzle (3200 = 8*400)
  int kc = wg >> 5;
  int n0 = (wg & 31) << 6;
  int tid = threadIdx.x;
  int lane = tid & 63, wv = tid >> 6;
  const short* Wk = W + (size_t)kc * DD;
  const float* mu = muK + (size_t)kc * DIM;
  int r16 = lane & 15;
  int k8 = (lane >> 4) << 3;
  int arow = (wv << 4) + r16;

  int lrow = lane >> 3;
  int lcolel = ((lane & 7) ^ lrow) << 3;

  constexpr int SJT[36] = {0,1,1, 2,3,2,3,2,3,3, 4,5,4,5,4,5,4,5,4,5,5,
                           6,7,6,7,6,7,6,7,6,7,6,7,6,7,7};
  constexpr int SDC[36] = {0,0,1, 0,0,1,1,2,2,3, 0,0,1,1,2,2,3,3,4,4,5,
                           0,0,1,1,2,2,3,3,4,4,5,5,6,6,7};

  bf16x8 af[8][2];
  #pragma unroll
  for (int dc = 0; dc < 8; ++dc) {
    #pragma unroll
    for (int ks = 0; ks < 2; ++ks) {
      int col = (dc << 6) + (ks << 5) + k8;
      const float* xp = X + (size_t)(n0 + arow)*DIM + col;
      float4 x0 = *(const float4*)xp;
      float4 x1 = *(const float4*)(xp + 4);
      float4 m0 = *(const float4*)(mu + col);
      float4 m1 = *(const float4*)(mu + col + 4);
      bf16x8 h;
      h[0]=f2bf(x0.x-m0.x); h[1]=f2bf(x0.y-m0.y); h[2]=f2bf(x0.z-m0.z); h[3]=f2bf(x0.w-m0.w);
      h[4]=f2bf(x1.x-m1.x); h[5]=f2bf(x1.y-m1.y); h[6]=f2bf(x1.z-m1.z); h[7]=f2bf(x1.w-m1.w);
      af[dc][ks] = h;
    }
  }

  auto issue = [&](int s) {
    const int b = s & 3;
    const int rbase = SJT[s] << 6;
    const int cc = (SDC[s] << 6) + lcolel;
    #pragma unroll
    for (int q = 0; q < 2; ++q) {
      const short* g = Wk + (size_t)(rbase + (q << 5) + (wv << 3) + lrow)*DIM + cc;
      __builtin_amdgcn_global_load_lds(
          (const __attribute__((address_space(1))) void*)g,
          (__attribute__((address_space(3))) void*)(WB4[b] + (q << 12) + (wv << 10)),
          16, 0, 0);
    }
  };

  float qp[4] = {0.f, 0.f, 0.f, 0.f};
  f32x4 acc[2][4];
  #pragma unroll
  for (int a = 0; a < 2; ++a)
    #pragma unroll
    for (int jj = 0; jj < 4; ++jj) { acc[a][jj][0]=0.f; acc[a][jj][1]=0.f; acc[a][jj][2]=0.f; acc[a][jj][3]=0.f; }

  issue(0);
  issue(1);
  #pragma unroll
  for (int s = 0; s < 36; ++s) {
    const int jt = SJT[s], dc = SDC[s];
    if (s + 2 < 36) issue(s + 2);
    if (s < 34)      asm volatile("s_waitcnt vmcnt(4)" ::: "memory");
    else if (s == 34) asm volatile("s_waitcnt vmcnt(2)" ::: "memory");
    else              asm volatile("s_waitcnt vmcnt(0)" ::: "memory");
    __builtin_amdgcn_s_barrier();
    __builtin_amdgcn_sched_barrier(0);
    __builtin_amdgcn_s_setprio(1);
    #pragma unroll
    for (int ks = 0; ks < 2; ++ks) {
      #pragma unroll
      for (int jj = 0; jj < 4; ++jj) {
        int brow = (jj << 4) + r16;
        bf16x8 bfr = *(const bf16x8*)((const char*)WB4[s & 3] +
                     (((brow << 7) + (((ks << 5) + k8) << 1)) ^ ((brow & 7) << 4)));
        acc[jt & 1][jj] = __builtin_amdgcn_mfma_f32_16x16x32_bf16(af[dc][ks], bfr, acc[jt & 1][jj], 0, 0, 0);
      }
    }
    __builtin_amdgcn_s_setprio(0);
    if (s == 2 || s == 9 || s == 20 || s == 35) {
      #pragma unroll
      for (int a = 0; a < 2; ++a)
        #pragma unroll
        for (int jj = 0; jj < 4; ++jj)
          #pragma unroll
          for (int r = 0; r < 4; ++r) {
            float y = acc[a][jj][r]; qp[r] += y * y;
            acc[a][jj][r] = 0.f;
          }
    }
  }
  #pragma unroll
  for (int r = 0; r < 4; ++r) {
    qp[r] += __shfl_xor(qp[r], 1);
    qp[r] += __shfl_xor(qp[r], 2);
    qp[r] += __shfl_xor(qp[r], 4);
    qp[r] += __shfl_xor(qp[r], 8);
  }
  {
    float v = (tid < NCLS) ? cK[tid] : 0.f;
    #pragma unroll
    for (int o = 32; o > 0; o >>= 1) v += __shfl_xor(v, o);
    if (lane == 0) sred[wv] = v;
  }
  __syncthreads();
  float sumck = sred[0] + sred[1] + sred[2] + sred[3];
  float ck = cK[kc];
  float base;
  if (ck == 0.f) base = -INFINITY;
  else base = logf(ck) - logf(sumck) - 0.25f * logf(aux[1 + kc]);
  if ((lane & 15) == 0) {
    int nbase = n0 + (wv << 4) + ((lane >> 4) << 2);
    #pragma unroll
    for (int r = 0; r < 4; ++r)
      out[(size_t)(nbase + r)*NCLS + kc] = base - 0.5f * qp[r];
  }
}

extern "C" void kernel_launch(void* const* d_in, const int* in_sizes, int n_in,
                              void* d_out, int out_size, void* d_ws, size_t ws_size,
                              hipStream_t stream) {
  (void)in_sizes; (void)n_in; (void)out_size; (void)ws_size;
  const float* X      = (const float*)d_in[0];
  const float* muK    = (const float*)d_in[1];
  const float* SigmaK = (const float*)d_in[2];
  const float* Sigma  = (const float*)d_in[3];
  const float* cK     = (const float*)d_in[4];
  float* out = (float*)d_out;
  char* ws = (char*)d_ws;
  float* M   = (float*)ws;                                   // 104857600 B
  short* W   = (short*)(ws + (size_t)NCLS * DD * 4);         //  52428800 B
  float* aux = (float*)(ws + (size_t)NCLS * DD * 6);         //       404 B

  hipMemsetAsync(aux, 0, (1 + NCLS) * sizeof(float), stream);
  prep_kernel<<<400, 256, 0, stream>>>(SigmaK, Sigma, M, aux);
  for (int p = 0; p < 8; ++p) {
    fdt_kernel<<<NCLS, 256, 0, stream>>>(M, W, p);
    int n = 7 - p;
    if (n > 0) syrk_kernel<<<NCLS * (n * (n + 1) / 2), 256, 0, stream>>>(M, p);
  }
  colsweep_kernel<<<NCLS * 7, 256, 0, stream>>>(M, W);
  score_kernel<<<NCLS * 32, 256, 0, stream>>>(X, muK, cK, W, aux, out);
}

// Round 10
// 798.497 us; speedup vs baseline: 1.5076x; 1.0910x over previous
//
#include <hip/hip_runtime.h>
#include <math.h>

#define DIM 512
#define NCLS 100
#define NS 2048
#define DD (DIM*DIM)
#define SHRINKV 1e-4f

typedef short bf16x8 __attribute__((ext_vector_type(8)));
typedef short s16x4 __attribute__((ext_vector_type(4)));
typedef float f32x4 __attribute__((ext_vector_type(4)));

static __device__ __forceinline__ short f2bf(float f) {
  unsigned int u = __float_as_uint(f);
  u += 0x7FFFu + ((u >> 16) & 1u);   // round-to-nearest-even
  return (short)(u >> 16);
}

// bijective XCD-contiguous remap (m204): consecutive wg -> same XCD chunk
static __device__ __forceinline__ int xcd_swz(int bid, int nwg) {
  int xcd = bid & 7, idx = bid >> 3;
  int q = nwg >> 3, r = nwg & 7;
  return (xcd < r ? xcd * (q + 1) : r * (q + 1) + (xcd - r) * q) + idx;
}

// Build M_k = (1-sh)*(0.5*(SigmaK_k+Sigma)) + sh*I ; accumulate ||RegSigma||_F^2
__global__ __launch_bounds__(256) void prep_kernel(const float* __restrict__ SigmaK,
                                                   const float* __restrict__ Sigma,
                                                   float* __restrict__ M,
                                                   float* __restrict__ aux) {
  int b = blockIdx.x;
  int k = b >> 2, chunk = b & 3;
  const float* Sk = SigmaK + (size_t)k * DD;
  float* Mk = M + (size_t)k * DD;
  int base0 = chunk << 16;
  float fro = 0.f;
  const float oms = 1.0f - SHRINKV;
  for (int it = 0; it < 64; ++it) {
    int idx = base0 + (it << 10) + (threadIdx.x << 2);
    float4 a = *(const float4*)(Sk + idx);
    float4 g = *(const float4*)(Sigma + idx);
    int r = idx >> 9, c = idx & 511;
    float4 reg;
    reg.x = 0.5f*(a.x + g.x); reg.y = 0.5f*(a.y + g.y);
    reg.z = 0.5f*(a.z + g.z); reg.w = 0.5f*(a.w + g.w);
    fro += reg.x*reg.x + reg.y*reg.y + reg.z*reg.z + reg.w*reg.w;
    float4 m;
    m.x = oms*reg.x + ((r == c + 0) ? SHRINKV : 0.f);
    m.y = oms*reg.y + ((r == c + 1) ? SHRINKV : 0.f);
    m.z = oms*reg.z + ((r == c + 2) ? SHRINKV : 0.f);
    m.w = oms*reg.w + ((r == c + 3) ? SHRINKV : 0.f);
    *(float4*)(Mk + idx) = m;
  }
  __shared__ float red[4];
  int lane = threadIdx.x & 63, w = threadIdx.x >> 6;
  for (int o = 32; o > 0; o >>= 1) fro += __shfl_down(fro, o);
  if (lane == 0) red[w] = fro;
  __syncthreads();
  if (threadIdx.x == 0) atomicAdd(&aux[1 + k], red[0] + red[1] + red[2] + red[3]);
}

// Single-wave (lane 0..63) diag factor + triangular inverse for panel at p0.
// Writes inv into M(p,p) f32 and W(p,p) bf16. Wave-synchronous: NO barriers.
static __device__ __forceinline__ void fdiag_dev(float* __restrict__ Mk,
                                                 short* __restrict__ Wk,
                                                 int p0, int lane,
                                                 float* __restrict__ Llds) {
  float row[64];
  const float* src = Mk + (size_t)(p0 + lane) * DIM + p0;
  #pragma unroll
  for (int c4 = 0; c4 < 64; c4 += 4) {
    float4 v = *(const float4*)(src + c4);
    row[c4] = v.x; row[c4+1] = v.y; row[c4+2] = v.z; row[c4+3] = v.w;
  }
  #pragma unroll
  for (int j = 0; j < 64; ++j) {
    float diagv = __shfl(row[j], j);
    float dv = sqrtf(diagv);
    float rinv = 1.0f / dv;
    float myLj = row[j] * rinv;
    row[j] = myLj;
    #pragma unroll
    for (int c = j + 1; c < 64; ++c)
      row[c] = fmaf(-myLj, __shfl(myLj, c), row[c]);
  }
  #pragma unroll
  for (int c = 0; c < 64; ++c)
    Llds[lane * 68 + c] = (c <= lane) ? row[c] : 0.f;
  // per-lane column solve: w[r] = inv[r][lane]
  float w[64];
  #pragma unroll
  for (int r = 0; r < 64; ++r) {
    float s = 0.f;
    #pragma unroll
    for (int kk = 0; kk + 4 <= r; kk += 4) {
      float4 lv = *(const float4*)(Llds + r*68 + kk);
      s += lv.x*w[kk] + lv.y*w[kk+1] + lv.z*w[kk+2] + lv.w*w[kk+3];
    }
    #pragma unroll
    for (int kk = r & ~3; kk < r; ++kk) s += Llds[r*68 + kk] * w[kk];
    float rhs = ((r == lane) ? 1.0f : 0.0f) - s;
    w[r] = rhs / Llds[r*68 + r];   // exact 0 for r < lane
  }
  #pragma unroll
  for (int r = 0; r < 64; ++r) {
    Mk[(size_t)(p0 + r)*DIM + p0 + lane] = w[r];
    Wk[(size_t)(p0 + r)*DIM + p0 + lane] = f2bf(w[r]);
  }
}

// Standalone fdiag for panel 0. One wave per class.
__global__ __launch_bounds__(64) void fdiag_kernel(float* __restrict__ M,
                                                   short* __restrict__ Wb) {
  __shared__ float Llds[64 * 68];
  fdiag_dev(M + (size_t)blockIdx.x * DD, Wb + (size_t)blockIdx.x * DD,
            0, threadIdx.x, Llds);
}

// TRSM for panel p: L_ip = A_ip * inv(p)^T. One WG per (class, i).
// The i==p+1 WG additionally folds the syrk self-update of block (p+1,p+1).
__global__ __launch_bounds__(256) void trsm_kernel(float* __restrict__ M, int p) {
  __shared__ float TA[64 * 68];
  __shared__ float TB[64 * 68];
  int n = 7 - p;
  int wg = xcd_swz(blockIdx.x, NCLS * n);
  int cls = wg / n, bi = wg % n;
  int i = p + 1 + bi;
  float* Mk = M + (size_t)cls * DD;
  int tid = threadIdx.x;
  int ty = tid >> 4, tx = tid & 15;
  int sr = tid >> 2, sq = (tid & 3) << 4;
  int p0 = p << 6;
  {
    const float* a = Mk + (size_t)((i << 6) + sr)*DIM + p0 + sq;
    const float* b = Mk + (size_t)(p0 + sr)*DIM + p0 + sq;   // inv(p)
    #pragma unroll
    for (int t4 = 0; t4 < 4; ++t4) {
      float4 va = *(const float4*)(a + 4*t4);
      TA[(sq+4*t4+0)*68+sr]=va.x; TA[(sq+4*t4+1)*68+sr]=va.y;
      TA[(sq+4*t4+2)*68+sr]=va.z; TA[(sq+4*t4+3)*68+sr]=va.w;
      float4 vb = *(const float4*)(b + 4*t4);
      TB[(sq+4*t4+0)*68+sr]=vb.x; TB[(sq+4*t4+1)*68+sr]=vb.y;
      TB[(sq+4*t4+2)*68+sr]=vb.z; TB[(sq+4*t4+3)*68+sr]=vb.w;
    }
  }
  __syncthreads();
  float acc[4][4];
  #pragma unroll
  for (int a2 = 0; a2 < 4; ++a2)
    #pragma unroll
    for (int b2 = 0; b2 < 4; ++b2) acc[a2][b2] = 0.f;
  #pragma unroll 16
  for (int m = 0; m < 64; ++m) {
    float4 av = *(const float4*)(TA + m*68 + (ty << 2));
    float4 bv = *(const float4*)(TB + m*68 + (tx << 2));
    float a4[4] = {av.x, av.y, av.z, av.w};
    float b4[4] = {bv.x, bv.y, bv.z, bv.w};
    #pragma unroll
    for (int ir = 0; ir < 4; ++ir)
      #pragma unroll
      for (int ic = 0; ic < 4; ++ic) acc[ir][ic] += a4[ir] * b4[ic];
  }
  #pragma unroll
  for (int q = 0; q < 4; ++q) {
    float4 v; v.x = acc[q][0]; v.y = acc[q][1]; v.z = acc[q][2]; v.w = acc[q][3];
    *(float4*)(Mk + (size_t)((i << 6) + (ty << 2) + q)*DIM + p0 + (tx << 2)) = v;
  }
  if (bi == 0) {   // fold syrk of (p+1,p+1): C -= L*L^T  (L = acc, in-register)
    __syncthreads();   // TA/TB reads done
    #pragma unroll
    for (int q = 0; q < 4; ++q)
      #pragma unroll
      for (int cc = 0; cc < 4; ++cc)
        TA[((tx << 2) + cc)*68 + (ty << 2) + q] = acc[q][cc];   // TA[m][r]=L[r][m]
    __syncthreads();
    float s2[4][4];
    #pragma unroll
    for (int a2 = 0; a2 < 4; ++a2)
      #pragma unroll
      for (int b2 = 0; b2 < 4; ++b2) s2[a2][b2] = 0.f;
    #pragma unroll 16
    for (int m = 0; m < 64; ++m) {
      float4 av = *(const float4*)(TA + m*68 + (ty << 2));
      float4 bv = *(const float4*)(TA + m*68 + (tx << 2));
      float a4[4] = {av.x, av.y, av.z, av.w};
      float b4[4] = {bv.x, bv.y, bv.z, bv.w};
      #pragma unroll
      for (int ir = 0; ir < 4; ++ir)
        #pragma unroll
        for (int ic = 0; ic < 4; ++ic) s2[ir][ic] += a4[ir] * b4[ic];
    }
    int d0 = (p + 1) << 6;
    #pragma unroll
    for (int q = 0; q < 4; ++q) {
      float* dst = Mk + (size_t)(d0 + (ty << 2) + q)*DIM + d0 + (tx << 2);
      float4 v = *(const float4*)dst;
      v.x -= s2[q][0]; v.y -= s2[q][1]; v.z -= s2[q][2]; v.w -= s2[q][3];
      *(float4*)dst = v;
    }
  }
}

// Combined launch for panel p: syrkR(p) (all pairs except (p+1,p+1)) in the
// first NCLS*(T-1) WGs, fdiag(p+1) in the last NCLS WGs (hidden under syrk).
__global__ __launch_bounds__(256) void combo_kernel(float* __restrict__ M,
                                                    short* __restrict__ Wb, int p) {
  __shared__ float TA[64 * 68];
  __shared__ float TB[64 * 68];
  int n = 7 - p;
  int T = n * (n + 1) / 2;
  int nsyrk = NCLS * (T - 1);
  int wg = xcd_swz(blockIdx.x, nsyrk + NCLS);
  int tid = threadIdx.x;
  if (wg >= nsyrk) {   // fdiag(p+1)
    int cls = wg - nsyrk;
    if (tid < 64)
      fdiag_dev(M + (size_t)cls * DD, Wb + (size_t)cls * DD,
                (p + 1) << 6, tid, TA);
    return;
  }
  int cls = wg / (T - 1);
  int t = wg % (T - 1) + 1;   // skip t=0 = (p+1,p+1), folded into trsm
  int bi = 0;
  while (t > bi) { t -= bi + 1; ++bi; }
  int i = p + 1 + bi, j = p + 1 + t;
  float* Mk = M + (size_t)cls * DD;
  int ty = tid >> 4, tx = tid & 15;
  int sr = tid >> 2, sq = (tid & 3) << 4;
  {
    const float* a = Mk + (size_t)((i << 6) + sr)*DIM + (p << 6) + sq;
    const float* b = Mk + (size_t)((j << 6) + sr)*DIM + (p << 6) + sq;
    #pragma unroll
    for (int t4 = 0; t4 < 4; ++t4) {
      float4 va = *(const float4*)(a + 4*t4);
      TA[(sq+4*t4+0)*68+sr]=va.x; TA[(sq+4*t4+1)*68+sr]=va.y;
      TA[(sq+4*t4+2)*68+sr]=va.z; TA[(sq+4*t4+3)*68+sr]=va.w;
      float4 vb = *(const float4*)(b + 4*t4);
      TB[(sq+4*t4+0)*68+sr]=vb.x; TB[(sq+4*t4+1)*68+sr]=vb.y;
      TB[(sq+4*t4+2)*68+sr]=vb.z; TB[(sq+4*t4+3)*68+sr]=vb.w;
    }
  }
  __syncthreads();
  float acc[4][4];
  #pragma unroll
  for (int a = 0; a < 4; ++a)
    #pragma unroll
    for (int b = 0; b < 4; ++b) acc[a][b] = 0.f;
  #pragma unroll 16
  for (int m = 0; m < 64; ++m) {
    float4 av = *(const float4*)(TA + m*68 + (ty << 2));
    float4 bv = *(const float4*)(TB + m*68 + (tx << 2));
    float a4[4] = {av.x, av.y, av.z, av.w};
    float b4[4] = {bv.x, bv.y, bv.z, bv.w};
    #pragma unroll
    for (int ir = 0; ir < 4; ++ir)
      #pragma unroll
      for (int ic = 0; ic < 4; ++ic) acc[ir][ic] += a4[ir] * b4[ic];
  }
  #pragma unroll
  for (int q = 0; q < 4; ++q) {
    float* dst = Mk + (size_t)((i << 6) + (ty << 2) + q)*DIM + (j << 6) + (tx << 2);
    float4 v = *(const float4*)dst;
    v.x -= acc[q][0]; v.y -= acc[q][1]; v.z -= acc[q][2]; v.w -= acc[q][3];
    *(float4*)dst = v;
  }
}

// Column sweep: one WG per (class, column j in 0..6). Double-buffered staging,
// XCD-swizzled so a class's 7 WGs share one XCD's L2.
__global__ __launch_bounds__(256) void colsweep_kernel(float* __restrict__ M,
                                                       short* __restrict__ Wb) {
  __shared__ float TL[2][64 * 68];
  __shared__ float TW[2][64 * 68];
  int wg = xcd_swz(blockIdx.x, NCLS * 7);
  int cls = wg / 7;
  int j = wg % 7;
  float* Mk = M + (size_t)cls * DD;
  short* Wk = Wb + (size_t)cls * DD;
  int tid = threadIdx.x;
  int ty = tid >> 4, tx = tid & 15;
  int sr = tid >> 2, sq = (tid & 3) << 4;
  for (int i = j + 1; i < 8; ++i) {
    auto stageLW = [&](int k, int buf) {
      const float* a = Mk + (size_t)((i << 6) + sr)*DIM + (k << 6) + sq;
      const float* b = Mk + (size_t)((j << 6) + sr)*DIM + (k << 6) + sq;
      #pragma unroll
      for (int t4 = 0; t4 < 4; ++t4) {
        float4 va = *(const float4*)(a + 4*t4);
        TL[buf][(sq+4*t4+0)*68+sr]=va.x; TL[buf][(sq+4*t4+1)*68+sr]=va.y;
        TL[buf][(sq+4*t4+2)*68+sr]=va.z; TL[buf][(sq+4*t4+3)*68+sr]=va.w;
        *(float4*)(TW[buf] + sr*68 + sq + 4*t4) = *(const float4*)(b + 4*t4);
      }
    };
    float acc[4][4];
    #pragma unroll
    for (int a = 0; a < 4; ++a)
      #pragma unroll
      for (int b = 0; b < 4; ++b) acc[a][b] = 0.f;
    stageLW(j, 0);
    __syncthreads();
    int cur = 0;
    for (int k = j; k < i; ++k) {
      if (k + 1 < i) stageLW(k + 1, cur ^ 1);   // overlaps GEMM below
      #pragma unroll 16
      for (int m = 0; m < 64; ++m) {
        float4 av = *(const float4*)(TL[cur] + m*68 + (ty << 2));
        float4 bv = *(const float4*)(TW[cur] + m*68 + (tx << 2));
        float a4[4] = {av.x, av.y, av.z, av.w};
        float b4[4] = {bv.x, bv.y, bv.z, bv.w};
        #pragma unroll
        for (int ir = 0; ir < 4; ++ir)
          #pragma unroll
          for (int ic = 0; ic < 4; ++ic) acc[ir][ic] += a4[ir] * b4[ic];
      }
      __syncthreads();
      cur ^= 1;
    }
    #pragma unroll
    for (int q = 0; q < 4; ++q) {
      float4 v; v.x = acc[q][0]; v.y = acc[q][1]; v.z = acc[q][2]; v.w = acc[q][3];
      *(float4*)(TW[0] + ((ty << 2) + q)*68 + (tx << 2)) = v;
    }
    {
      const float* a = Mk + (size_t)((i << 6) + sr)*DIM + (i << 6) + sq;
      #pragma unroll
      for (int t4 = 0; t4 < 4; ++t4) {
        float4 va = *(const float4*)(a + 4*t4);
        TL[0][(sq+4*t4+0)*68+sr]=va.x; TL[0][(sq+4*t4+1)*68+sr]=va.y;
        TL[0][(sq+4*t4+2)*68+sr]=va.z; TL[0][(sq+4*t4+3)*68+sr]=va.w;
      }
    }
    __syncthreads();
    float r2[4][4];
    #pragma unroll
    for (int a = 0; a < 4; ++a)
      #pragma unroll
      for (int b = 0; b < 4; ++b) r2[a][b] = 0.f;
    #pragma unroll 16
    for (int m = 0; m < 64; ++m) {
      float4 av = *(const float4*)(TL[0] + m*68 + (ty << 2));
      float4 bv = *(const float4*)(TW[0] + m*68 + (tx << 2));
      float a4[4] = {av.x, av.y, av.z, av.w};
      float b4[4] = {bv.x, bv.y, bv.z, bv.w};
      #pragma unroll
      for (int ir = 0; ir < 4; ++ir)
        #pragma unroll
        for (int ic = 0; ic < 4; ++ic) r2[ir][ic] += a4[ir] * b4[ic];
    }
    #pragma unroll
    for (int q = 0; q < 4; ++q) {
      int a = (ty << 2) + q;
      float4 v; v.x = -r2[q][0]; v.y = -r2[q][1]; v.z = -r2[q][2]; v.w = -r2[q][3];
      *(float4*)(Mk + (size_t)((j << 6) + a)*DIM + (i << 6) + (tx << 2)) = v;
      s16x4 h;
      h[0] = f2bf(v.x); h[1] = f2bf(v.y); h[2] = f2bf(v.z); h[3] = f2bf(v.w);
      *(s16x4*)(Wk + (size_t)((i << 6) + a)*DIM + (j << 6) + (tx << 2)) = h;
    }
    __syncthreads();
  }
}

// scores via bf16 MFMA. W tiles staged via global_load_lds into a 4-buffer
// ring, depth-2 pipeline with counted vmcnt + raw barriers (T3+T4).
__global__ __launch_bounds__(256) void score_kernel(const float* __restrict__ X,
                                                    const float* __restrict__ muK,
                                                    const float* __restrict__ cK,
                                                    const short* __restrict__ W,
                                                    const float* __restrict__ aux,
                                                    float* __restrict__ out) {
  __shared__ __align__(16) char WB4[4][8192];
  __shared__ float sred[4];
  int bid = blockIdx.x;
  int wg = ((bid & 7) * 400) + (bid >> 3);   // XCD swizzle (3200 = 8*400)
  int kc = wg >> 5;
  int n0 = (wg & 31) << 6;
  int tid = threadIdx.x;
  int lane = tid & 63, wv = tid >> 6;
  const short* Wk = W + (size_t)kc * DD;
  const float* mu = muK + (size_t)kc * DIM;
  int r16 = lane & 15;
  int k8 = (lane >> 4) << 3;
  int arow = (wv << 4) + r16;

  int lrow = lane >> 3;
  int lcolel = ((lane & 7) ^ lrow) << 3;

  constexpr int SJT[36] = {0,1,1, 2,3,2,3,2,3,3, 4,5,4,5,4,5,4,5,4,5,5,
                           6,7,6,7,6,7,6,7,6,7,6,7,6,7,7};
  constexpr int SDC[36] = {0,0,1, 0,0,1,1,2,2,3, 0,0,1,1,2,2,3,3,4,4,5,
                           0,0,1,1,2,2,3,3,4,4,5,5,6,6,7};

  bf16x8 af[8][2];
  #pragma unroll
  for (int dc = 0; dc < 8; ++dc) {
    #pragma unroll
    for (int ks = 0; ks < 2; ++ks) {
      int col = (dc << 6) + (ks << 5) + k8;
      const float* xp = X + (size_t)(n0 + arow)*DIM + col;
      float4 x0 = *(const float4*)xp;
      float4 x1 = *(const float4*)(xp + 4);
      float4 m0 = *(const float4*)(mu + col);
      float4 m1 = *(const float4*)(mu + col + 4);
      bf16x8 h;
      h[0]=f2bf(x0.x-m0.x); h[1]=f2bf(x0.y-m0.y); h[2]=f2bf(x0.z-m0.z); h[3]=f2bf(x0.w-m0.w);
      h[4]=f2bf(x1.x-m1.x); h[5]=f2bf(x1.y-m1.y); h[6]=f2bf(x1.z-m1.z); h[7]=f2bf(x1.w-m1.w);
      af[dc][ks] = h;
    }
  }

  auto issue = [&](int s) {
    const int b = s & 3;
    const int rbase = SJT[s] << 6;
    const int cc = (SDC[s] << 6) + lcolel;
    #pragma unroll
    for (int q = 0; q < 2; ++q) {
      const short* g = Wk + (size_t)(rbase + (q << 5) + (wv << 3) + lrow)*DIM + cc;
      __builtin_amdgcn_global_load_lds(
          (const __attribute__((address_space(1))) void*)g,
          (__attribute__((address_space(3))) void*)(WB4[b] + (q << 12) + (wv << 10)),
          16, 0, 0);
    }
  };

  float qp[4] = {0.f, 0.f, 0.f, 0.f};
  f32x4 acc[2][4];
  #pragma unroll
  for (int a = 0; a < 2; ++a)
    #pragma unroll
    for (int jj = 0; jj < 4; ++jj) { acc[a][jj][0]=0.f; acc[a][jj][1]=0.f; acc[a][jj][2]=0.f; acc[a][jj][3]=0.f; }

  issue(0);
  issue(1);
  #pragma unroll
  for (int s = 0; s < 36; ++s) {
    const int jt = SJT[s], dc = SDC[s];
    if (s + 2 < 36) issue(s + 2);
    if (s < 34)      asm volatile("s_waitcnt vmcnt(4)" ::: "memory");
    else if (s == 34) asm volatile("s_waitcnt vmcnt(2)" ::: "memory");
    else              asm volatile("s_waitcnt vmcnt(0)" ::: "memory");
    __builtin_amdgcn_s_barrier();
    __builtin_amdgcn_sched_barrier(0);
    __builtin_amdgcn_s_setprio(1);
    #pragma unroll
    for (int ks = 0; ks < 2; ++ks) {
      #pragma unroll
      for (int jj = 0; jj < 4; ++jj) {
        int brow = (jj << 4) + r16;
        bf16x8 bfr = *(const bf16x8*)((const char*)WB4[s & 3] +
                     (((brow << 7) + (((ks << 5) + k8) << 1)) ^ ((brow & 7) << 4)));
        acc[jt & 1][jj] = __builtin_amdgcn_mfma_f32_16x16x32_bf16(af[dc][ks], bfr, acc[jt & 1][jj], 0, 0, 0);
      }
    }
    __builtin_amdgcn_s_setprio(0);
    if (s == 2 || s == 9 || s == 20 || s == 35) {
      #pragma unroll
      for (int a = 0; a < 2; ++a)
        #pragma unroll
        for (int jj = 0; jj < 4; ++jj)
          #pragma unroll
          for (int r = 0; r < 4; ++r) {
            float y = acc[a][jj][r]; qp[r] += y * y;
            acc[a][jj][r] = 0.f;
          }
    }
  }
  #pragma unroll
  for (int r = 0; r < 4; ++r) {
    qp[r] += __shfl_xor(qp[r], 1);
    qp[r] += __shfl_xor(qp[r], 2);
    qp[r] += __shfl_xor(qp[r], 4);
    qp[r] += __shfl_xor(qp[r], 8);
  }
  {
    float v = (tid < NCLS) ? cK[tid] : 0.f;
    #pragma unroll
    for (int o = 32; o > 0; o >>= 1) v += __shfl_xor(v, o);
    if (lane == 0) sred[wv] = v;
  }
  __syncthreads();
  float sumck = sred[0] + sred[1] + sred[2] + sred[3];
  float ck = cK[kc];
  float base;
  if (ck == 0.f) base = -INFINITY;
  else base = logf(ck) - logf(sumck) - 0.25f * logf(aux[1 + kc]);
  if ((lane & 15) == 0) {
    int nbase = n0 + (wv << 4) + ((lane >> 4) << 2);
    #pragma unroll
    for (int r = 0; r < 4; ++r)
      out[(size_t)(nbase + r)*NCLS + kc] = base - 0.5f * qp[r];
  }
}

extern "C" void kernel_launch(void* const* d_in, const int* in_sizes, int n_in,
                              void* d_out, int out_size, void* d_ws, size_t ws_size,
                              hipStream_t stream) {
  (void)in_sizes; (void)n_in; (void)out_size; (void)ws_size;
  const float* X      = (const float*)d_in[0];
  const float* muK    = (const float*)d_in[1];
  const float* SigmaK = (const float*)d_in[2];
  const float* Sigma  = (const float*)d_in[3];
  const float* cK     = (const float*)d_in[4];
  float* out = (float*)d_out;
  char* ws = (char*)d_ws;
  float* M   = (float*)ws;                                   // 104857600 B
  short* W   = (short*)(ws + (size_t)NCLS * DD * 4);         //  52428800 B
  float* aux = (float*)(ws + (size_t)NCLS * DD * 6);         //       404 B

  hipMemsetAsync(aux, 0, (1 + NCLS) * sizeof(float), stream);
  prep_kernel<<<400, 256, 0, stream>>>(SigmaK, Sigma, M, aux);
  fdiag_kernel<<<NCLS, 64, 0, stream>>>(M, W);               // panel 0 diag
  for (int p = 0; p < 7; ++p) {
    int n = 7 - p;
    int T = n * (n + 1) / 2;
    trsm_kernel<<<NCLS * n, 256, 0, stream>>>(M, p);         // + (p+1,p+1) fold
    combo_kernel<<<NCLS * (T - 1) + NCLS, 256, 0, stream>>>(M, W, p);  // syrkR ∥ fdiag(p+1)
  }
  colsweep_kernel<<<NCLS * 7, 256, 0, stream>>>(M, W);
  score_kernel<<<NCLS * 32, 256, 0, stream>>>(X, muK, cK, W, aux, out);
}